// Round 1
// baseline (32510.635 us; speedup 1.0000x reference)
//
#include <hip/hip_runtime.h>
#include <math.h>

// Sizes (fixed by the problem)
#define NBG 300   // graphs

__device__ __forceinline__ float sigmoidf_(float x){ return 1.0f/(1.0f+expf(-x)); }

// ---------- lin0: out = relu(x @ lin0_w.T + b)  [N,14]->[N,64] ----------
__global__ void lin0_kernel(const float* __restrict__ x, const float* __restrict__ w,
                            const float* __restrict__ b, float* __restrict__ out, int N){
  int n = blockIdx.x; int d = threadIdx.x;
  __shared__ float xs[16];
  if (d < 14) xs[d] = x[n*14 + d];
  __syncthreads();
  float acc = b[d];
  #pragma unroll
  for (int k = 0; k < 14; ++k) acc = fmaf(xs[k], w[d*14 + k], acc);
  out[n*64 + d] = fmaxf(acc, 0.0f);
}

// ---------- edge MLP hidden: relu(edge_attr @ nn1_w.T + b)  [E,4]->[E,128] ----------
__global__ void ehid_kernel(const float* __restrict__ ea, const float* __restrict__ w,
                            const float* __restrict__ b, float* __restrict__ hid, int E){
  int e = blockIdx.x; int t = threadIdx.x;
  __shared__ float as[4];
  if (t < 4) as[t] = ea[e*4 + t];
  __syncthreads();
  float acc = b[t];
  #pragma unroll
  for (int k = 0; k < 4; ++k) acc = fmaf(as[k], w[t*4 + k], acc);
  hid[e*128 + t] = fmaxf(acc, 0.0f);
}

// ---------- degree (counts into dst) ----------
__global__ void deg_kernel(const int* __restrict__ dst, float* __restrict__ deg, int E){
  int e = blockIdx.x*blockDim.x + threadIdx.x;
  if (e < E) atomicAdd(&deg[dst[e]], 1.0f);
}

// ---------- W_e GEMM: We[E,4096] = hidden[E,128] @ nn2_w.T + b2 ----------
#define BM 128
#define BN 128
#define BK 32
__global__ __launch_bounds__(256) void we_gemm(const float* __restrict__ H,
    const float* __restrict__ W2, const float* __restrict__ b2,
    float* __restrict__ We, int E){
  __shared__ float As[BK][BM];   // As[k][m]
  __shared__ float Bs[BK][BN];   // Bs[k][n]
  int bm = blockIdx.x*BM, bn = blockIdx.y*BN;
  int tid = threadIdx.x;
  int tx = tid & 15, ty = tid >> 4;   // tx->n, ty->m
  float acc[8][8];
  #pragma unroll
  for (int r = 0; r < 8; ++r)
    #pragma unroll
    for (int c = 0; c < 8; ++c) acc[r][c] = 0.0f;

  for (int k0 = 0; k0 < 128; k0 += BK){
    #pragma unroll
    for (int l = 0; l < 4; ++l){
      int idx = tid + l*256;          // 0..1023 float4 slots
      int m = idx >> 3, kq = idx & 7;
      int e = bm + m;
      float4 v = make_float4(0.f,0.f,0.f,0.f);
      if (e < E) v = *(const float4*)(H + (size_t)e*128 + k0 + kq*4);
      As[kq*4+0][m]=v.x; As[kq*4+1][m]=v.y; As[kq*4+2][m]=v.z; As[kq*4+3][m]=v.w;
    }
    #pragma unroll
    for (int l = 0; l < 4; ++l){
      int idx = tid + l*256;
      int n = idx >> 3, kq = idx & 7;
      float4 v = *(const float4*)(W2 + (size_t)(bn+n)*128 + k0 + kq*4);
      Bs[kq*4+0][n]=v.x; Bs[kq*4+1][n]=v.y; Bs[kq*4+2][n]=v.z; Bs[kq*4+3][n]=v.w;
    }
    __syncthreads();
    #pragma unroll 2
    for (int k = 0; k < BK; ++k){
      float a[8], bb[8];
      *(float4*)&a[0]  = *(const float4*)&As[k][ty*8];
      *(float4*)&a[4]  = *(const float4*)&As[k][ty*8+4];
      *(float4*)&bb[0] = *(const float4*)&Bs[k][tx*8];
      *(float4*)&bb[4] = *(const float4*)&Bs[k][tx*8+4];
      #pragma unroll
      for (int r = 0; r < 8; ++r)
        #pragma unroll
        for (int c = 0; c < 8; ++c)
          acc[r][c] = fmaf(a[r], bb[c], acc[r][c]);
    }
    __syncthreads();
  }
  #pragma unroll
  for (int r = 0; r < 8; ++r){
    int e = bm + ty*8 + r;
    if (e >= E) continue;
    float ob[8];
    #pragma unroll
    for (int c = 0; c < 8; ++c) ob[c] = acc[r][c] + b2[bn + tx*8 + c];
    *(float4*)(We + (size_t)e*4096 + bn + tx*8)     = *(float4*)&ob[0];
    *(float4*)(We + (size_t)e*4096 + bn + tx*8 + 4) = *(float4*)&ob[4];
  }
}

// ---------- message + scatter (materialized W_e) ----------
__global__ void msg_kernel(const float* __restrict__ We, const float* __restrict__ out,
                           const int* __restrict__ src, const int* __restrict__ dst,
                           float* __restrict__ agg, int E){
  int e = blockIdx.x; int o = threadIdx.x;
  __shared__ float s[64];
  s[o] = out[src[e]*64 + o];
  __syncthreads();
  const float* W = We + (size_t)e*4096;
  float acc = 0.0f;
  #pragma unroll 16
  for (int i = 0; i < 64; ++i) acc = fmaf(s[i], W[i*64 + o], acc);
  atomicAdd(&agg[dst[e]*64 + o], acc);
}

// ---------- message + scatter (fused fallback, recompute W on the fly) ----------
__global__ void msg_fused_kernel(const float* __restrict__ hid, const float* __restrict__ w2,
                                 const float* __restrict__ b2, const float* __restrict__ out,
                                 const int* __restrict__ src, const int* __restrict__ dst,
                                 float* __restrict__ agg, int E){
  int e = blockIdx.x; int o = threadIdx.x;
  __shared__ float s[64];
  __shared__ float hsh[128];
  s[o] = out[src[e]*64 + o];
  hsh[o] = hid[e*128 + o];
  hsh[64 + o] = hid[e*128 + 64 + o];
  __syncthreads();
  float acc = 0.0f;
  for (int i = 0; i < 64; ++i){
    const float* wr = w2 + (size_t)(i*64 + o)*128;
    float wv = b2[i*64 + o];
    #pragma unroll 8
    for (int h = 0; h < 128; ++h) wv = fmaf(hsh[h], wr[h], wv);
    acc = fmaf(s[i], wv, acc);
  }
  atomicAdd(&agg[dst[e]*64 + o], acc);
}

// ---------- node update: m = relu(out@root_w + agg/deg + conv_b); GRU ----------
__global__ void node_kernel(const float* __restrict__ root_w, const float* __restrict__ conv_b,
                            const float* __restrict__ wih, const float* __restrict__ whh,
                            const float* __restrict__ bih, const float* __restrict__ bhh,
                            const float* __restrict__ agg, const float* __restrict__ deg,
                            float* __restrict__ out, int N){
  int n = blockIdx.x; int d = threadIdx.x;
  __shared__ float row[64];   // out == h
  __shared__ float mrow[64];
  row[d] = out[n*64 + d];
  __syncthreads();
  float acc = conv_b[d] + agg[n*64 + d] / fmaxf(deg[n], 1.0f);
  #pragma unroll 8
  for (int i = 0; i < 64; ++i) acc = fmaf(row[i], root_w[i*64 + d], acc);
  float m = fmaxf(acc, 0.0f);
  mrow[d] = m;
  __syncthreads();
  float gxr = bih[d], gxz = bih[64+d], gxn = bih[128+d];
  float ghr = bhh[d], ghz = bhh[64+d], ghn = bhh[128+d];
  #pragma unroll 4
  for (int k = 0; k < 64; ++k){
    float mk = mrow[k], hk = row[k];
    gxr = fmaf(mk, wih[d*64 + k], gxr);
    gxz = fmaf(mk, wih[(64+d)*64 + k], gxz);
    gxn = fmaf(mk, wih[(128+d)*64 + k], gxn);
    ghr = fmaf(hk, whh[d*64 + k], ghr);
    ghz = fmaf(hk, whh[(64+d)*64 + k], ghz);
    ghn = fmaf(hk, whh[(128+d)*64 + k], ghn);
  }
  float r = sigmoidf_(gxr + ghr);
  float z = sigmoidf_(gxz + ghz);
  float nn = tanhf(gxn + r*ghn);
  out[n*64 + d] = (1.0f - z)*nn + z*row[d];
}

// ---------- Set2Set LSTM step ----------
__global__ void lstm_kernel(const float* __restrict__ wih, const float* __restrict__ whh,
                            const float* __restrict__ bih, const float* __restrict__ bhh,
                            const float* __restrict__ qstar, float* __restrict__ hs,
                            float* __restrict__ cs, int B){
  int b = blockIdx.x; int t = threadIdx.x;   // 256 threads
  __shared__ float q[128];
  __shared__ float h[64];
  __shared__ float g[256];
  if (t < 128) q[t] = qstar[b*128 + t];
  if (t < 64)  h[t] = hs[b*64 + t];
  __syncthreads();
  float acc = bih[t] + bhh[t];
  #pragma unroll 8
  for (int k = 0; k < 128; ++k) acc = fmaf(q[k], wih[t*128 + k], acc);
  #pragma unroll 8
  for (int k = 0; k < 64;  ++k) acc = fmaf(h[k], whh[t*64 + k], acc);
  g[t] = acc;
  __syncthreads();
  if (t < 64){
    float ig = sigmoidf_(g[t]);
    float fg = sigmoidf_(g[64 + t]);
    float gg = tanhf(g[128 + t]);
    float og = sigmoidf_(g[192 + t]);
    float c = fg*cs[b*64 + t] + ig*gg;
    cs[b*64 + t] = c;
    hs[b*64 + t] = og*tanhf(c);
  }
}

// ---------- attention: e = dot(out[n], q[batch[n]]), segment max via ordered-uint atomicMax ----------
__global__ void attn_e_kernel(const float* __restrict__ out, const float* __restrict__ hs,
                              const int* __restrict__ batch, float* __restrict__ evals,
                              unsigned int* __restrict__ emaxk, int N){
  int n = blockIdx.x; int d = threadIdx.x;  // 64 = one wave
  int b = batch[n];
  float p = out[n*64 + d] * hs[b*64 + d];
  #pragma unroll
  for (int off = 32; off > 0; off >>= 1) p += __shfl_down(p, off, 64);
  if (d == 0){
    evals[n] = p;
    unsigned u = __float_as_uint(p);
    unsigned key = (u & 0x80000000u) ? ~u : (u | 0x80000000u);
    atomicMax(&emaxk[b], key);
  }
}

__global__ void attn_exp_kernel(const float* __restrict__ evals, const unsigned int* __restrict__ emaxk,
                                const int* __restrict__ batch, float* __restrict__ avals,
                                float* __restrict__ asum, int N){
  int n = blockIdx.x*blockDim.x + threadIdx.x;
  if (n >= N) return;
  int b = batch[n];
  unsigned key = emaxk[b];
  unsigned u = (key & 0x80000000u) ? (key ^ 0x80000000u) : ~key;
  float mx = __uint_as_float(u);
  float a = expf(evals[n] - mx);
  avals[n] = a;
  atomicAdd(&asum[b], a);
}

__global__ void attn_r_kernel(const float* __restrict__ out, const float* __restrict__ avals,
                              const float* __restrict__ asum, const int* __restrict__ batch,
                              float* __restrict__ rread, int N){
  int n = blockIdx.x; int d = threadIdx.x;
  int b = batch[n];
  float w = avals[n] / asum[b];
  atomicAdd(&rread[b*64 + d], w * out[n*64 + d]);
}

__global__ void qstar_kernel(const float* __restrict__ hs, const float* __restrict__ rread,
                             float* __restrict__ qstar, int B){
  int b = blockIdx.x; int t = threadIdx.x;  // 128
  qstar[b*128 + t] = (t < 64) ? hs[b*64 + t] : rread[b*64 + (t - 64)];
}

// ---------- readout: y = lin2(relu(lin1(q_star))) ----------
__global__ void readout_kernel(const float* __restrict__ qstar, const float* __restrict__ w1,
                               const float* __restrict__ b1, const float* __restrict__ w2,
                               const float* __restrict__ b2, float* __restrict__ y, int B){
  int b = blockIdx.x; int t = threadIdx.x;   // 64
  __shared__ float q[128];
  q[t] = qstar[b*128 + t];
  q[64 + t] = qstar[b*128 + 64 + t];
  __syncthreads();
  float acc = b1[t];
  #pragma unroll 8
  for (int k = 0; k < 128; ++k) acc = fmaf(q[k], w1[t*128 + k], acc);
  float v = fmaxf(acc, 0.0f) * w2[t];
  #pragma unroll
  for (int off = 32; off > 0; off >>= 1) v += __shfl_down(v, off, 64);
  if (t == 0) y[b] = v + b2[0];
}

__global__ void copy_kernel(const float* __restrict__ in, float* __restrict__ dst, int n){
  int i = blockIdx.x*blockDim.x + threadIdx.x;
  if (i < n) dst[i] = in[i];
}

extern "C" void kernel_launch(void* const* d_in, const int* in_sizes, int n_in,
                              void* d_out, int out_size, void* d_ws, size_t ws_size,
                              hipStream_t stream){
  const float* x      = (const float*)d_in[0];
  const int*   ei     = (const int*)  d_in[1];
  const float* ea     = (const float*)d_in[2];
  const int*   batch  = (const int*)  d_in[3];
  const float* lin0_w = (const float*)d_in[4];
  const float* lin0_b = (const float*)d_in[5];
  const float* nn1_w  = (const float*)d_in[6];
  const float* nn1_b  = (const float*)d_in[7];
  const float* nn2_w  = (const float*)d_in[8];
  const float* nn2_b  = (const float*)d_in[9];
  const float* root_w = (const float*)d_in[10];
  const float* conv_b = (const float*)d_in[11];
  const float* gwih   = (const float*)d_in[12];
  const float* gwhh   = (const float*)d_in[13];
  const float* gbih   = (const float*)d_in[14];
  const float* gbhh   = (const float*)d_in[15];
  const float* lwih   = (const float*)d_in[16];
  const float* lwhh   = (const float*)d_in[17];
  const float* lbih   = (const float*)d_in[18];
  const float* lbhh   = (const float*)d_in[19];
  const float* l1w    = (const float*)d_in[20];
  const float* l1b    = (const float*)d_in[21];
  const float* l2w    = (const float*)d_in[22];
  const float* l2b    = (const float*)d_in[23];

  const int N = in_sizes[0] / 14;
  const int E = in_sizes[1] / 2;
  const int B = NBG;
  const int* src  = ei;
  const int* dstv = ei + E;

  char* wsp = (char*)d_ws; size_t off = 0;
  auto alloc = [&](size_t bytes)->char* {
    char* p = wsp + off; off += (bytes + 255) & ~((size_t)255); return p;
  };
  float* out    = (float*)alloc((size_t)N*64*4);
  float* agg    = (float*)alloc((size_t)N*64*4);
  float* deg    = (float*)alloc((size_t)N*4);
  float* evals  = (float*)alloc((size_t)N*4);
  float* avals  = (float*)alloc((size_t)N*4);
  float* qstar  = (float*)alloc((size_t)B*128*4);
  float* hs     = (float*)alloc((size_t)B*64*4);
  float* cs     = (float*)alloc((size_t)B*64*4);
  float* rread  = (float*)alloc((size_t)B*64*4);
  float* asum   = (float*)alloc((size_t)B*4);
  unsigned int* emaxk = (unsigned int*)alloc((size_t)B*4);
  float* hidden = (float*)alloc((size_t)E*128*4);
  size_t we_bytes = (size_t)E*4096*4;
  float* We = nullptr;
  if (ws_size >= off + we_bytes + 256) We = (float*)alloc(we_bytes);

  lin0_kernel<<<N, 64, 0, stream>>>(x, lin0_w, lin0_b, out, N);
  ehid_kernel<<<E, 128, 0, stream>>>(ea, nn1_w, nn1_b, hidden, E);
  hipMemsetAsync(deg, 0, (size_t)N*4, stream);
  deg_kernel<<<(E + 255)/256, 256, 0, stream>>>(dstv, deg, E);

  if (We){
    dim3 g((E + BM - 1)/BM, 4096/BN);
    we_gemm<<<g, 256, 0, stream>>>(hidden, nn2_w, nn2_b, We, E);
  }

  for (int it = 0; it < 3; ++it){
    hipMemsetAsync(agg, 0, (size_t)N*64*4, stream);
    if (We)
      msg_kernel<<<E, 64, 0, stream>>>(We, out, src, dstv, agg, E);
    else
      msg_fused_kernel<<<E, 64, 0, stream>>>(hidden, nn2_w, nn2_b, out, src, dstv, agg, E);
    node_kernel<<<N, 64, 0, stream>>>(root_w, conv_b, gwih, gwhh, gbih, gbhh, agg, deg, out, N);
  }

  hipMemsetAsync(qstar, 0, (size_t)B*128*4, stream);
  hipMemsetAsync(hs, 0, (size_t)B*64*4, stream);
  hipMemsetAsync(cs, 0, (size_t)B*64*4, stream);
  for (int s = 0; s < 3; ++s){
    lstm_kernel<<<B, 256, 0, stream>>>(lwih, lwhh, lbih, lbhh, qstar, hs, cs, B);
    hipMemsetAsync(emaxk, 0, (size_t)B*4, stream);
    hipMemsetAsync(asum, 0, (size_t)B*4, stream);
    hipMemsetAsync(rread, 0, (size_t)B*64*4, stream);
    attn_e_kernel<<<N, 64, 0, stream>>>(out, hs, batch, evals, emaxk, N);
    attn_exp_kernel<<<(N + 255)/256, 256, 0, stream>>>(evals, emaxk, batch, avals, asum, N);
    attn_r_kernel<<<N, 64, 0, stream>>>(out, avals, asum, batch, rread, N);
    qstar_kernel<<<B, 128, 0, stream>>>(hs, rread, qstar, B);
  }

  readout_kernel<<<B, 64, 0, stream>>>(qstar, l1w, l1b, l2w, l2b, (float*)d_out, B);
  copy_kernel<<<((size_t)N*64 + 255)/256, 256, 0, stream>>>(out, (float*)d_out + 300, N*64);
}

// Round 2
// 1520.685 us; speedup vs baseline: 21.3789x; 21.3789x over previous
//
#include <hip/hip_runtime.h>
#include <hip/hip_bf16.h>
#include <math.h>

#define NBG 300
#define KP 8256   // K dimension: 64*128 (i,h) + 64 (svec rows for nn2_b term)

typedef __attribute__((ext_vector_type(8))) short short8_t;
typedef __attribute__((ext_vector_type(4))) float f32x4_t;

__device__ __forceinline__ float sigmoidf_(float x){ return 1.0f/(1.0f+expf(-x)); }

// ---------- lin0: out = relu(x @ lin0_w.T + b)  [N,14]->[N,64] ----------
__global__ void lin0_kernel(const float* __restrict__ x, const float* __restrict__ w,
                            const float* __restrict__ b, float* __restrict__ out, int N){
  int n = blockIdx.x; int d = threadIdx.x;
  __shared__ float xs[16];
  if (d < 14) xs[d] = x[n*14 + d];
  __syncthreads();
  float acc = b[d];
  #pragma unroll
  for (int k = 0; k < 14; ++k) acc = fmaf(xs[k], w[d*14 + k], acc);
  out[n*64 + d] = fmaxf(acc, 0.0f);
}

// ---------- edge MLP hidden: relu(edge_attr @ nn1_w.T + b)  [E,4]->[E,128] ----------
__global__ void ehid_kernel(const float* __restrict__ ea, const float* __restrict__ w,
                            const float* __restrict__ b, float* __restrict__ hid, int E){
  int e = blockIdx.x; int t = threadIdx.x;
  __shared__ float as[4];
  if (t < 4) as[t] = ea[e*4 + t];
  __syncthreads();
  float acc = b[t];
  #pragma unroll
  for (int k = 0; k < 4; ++k) acc = fmaf(as[k], w[t*4 + k], acc);
  hid[(size_t)e*128 + t] = fmaxf(acc, 0.0f);
}

// ---------- counting sort of edges by dst ----------
__global__ void count_kernel(const int* __restrict__ dst, int* __restrict__ counts, int E){
  int e = blockIdx.x*blockDim.x + threadIdx.x;
  if (e < E) atomicAdd(&counts[dst[e]], 1);
}

__global__ __launch_bounds__(1024) void scan_kernel(const int* __restrict__ counts,
    int* __restrict__ starts, int* __restrict__ cursor, int N){
  __shared__ int part[1024];
  int t = threadIdx.x;
  int per = (N + 1023) >> 10;
  int base = t * per;
  int s = 0;
  for (int j = 0; j < per; ++j){ int idx = base + j; if (idx < N) s += counts[idx]; }
  part[t] = s;
  __syncthreads();
  for (int off = 1; off < 1024; off <<= 1){
    int v = (t >= off) ? part[t - off] : 0;
    __syncthreads();
    part[t] += v;
    __syncthreads();
  }
  int run = (t == 0) ? 0 : part[t-1];
  for (int j = 0; j < per; ++j){
    int idx = base + j;
    if (idx < N){ starts[idx] = run; cursor[idx] = run; run += counts[idx]; }
  }
}

__global__ void scatter_kernel(const int* __restrict__ dst, int* __restrict__ cursor,
                               int* __restrict__ sorted_eid, int E){
  int e = blockIdx.x*blockDim.x + threadIdx.x;
  if (e < E){ int p = atomicAdd(&cursor[dst[e]], 1); sorted_eid[p] = e; }
}

// ---------- W2t build: W2t[o][i*128+h] = nn2_w[i*64+o][h]; W2t[o][8192+i] = b2[i*64+o] ----------
__global__ void w2t_build(const float* __restrict__ w2, const float* __restrict__ b2,
                          __hip_bfloat16* __restrict__ W2t){
  int o = blockIdx.x;   // 64 blocks
  for (int k = threadIdx.x; k < KP; k += blockDim.x){
    float val;
    if (k < 8192){ int i = k >> 7, h = k & 127; val = w2[(size_t)(i*64 + o)*128 + h]; }
    else val = b2[(k - 8192)*64 + o];
    W2t[(size_t)o*KP + k] = __float2bfloat16(val);
  }
}

// ---------- Ksum build: per-node sum of outer(out[src], hid[e]) + svec, bf16 ----------
__global__ __launch_bounds__(256) void ksum_build(const float* __restrict__ out,
    const float* __restrict__ hidden, const int* __restrict__ sorted_eid,
    const int* __restrict__ starts, const int* __restrict__ counts,
    const int* __restrict__ src, __hip_bfloat16* __restrict__ Ksum, int c0){
  int v = c0 + blockIdx.x;
  int t = threadIdx.x;
  __shared__ float sbuf[64];
  __shared__ float hbuf[128];
  float acc[32];
  #pragma unroll
  for (int j = 0; j < 32; ++j) acc[j] = 0.f;
  float ssum = 0.f;
  int e0 = starts[v], cnt = counts[v];
  int i = t >> 2, h0 = (t & 3) * 32;
  for (int k = 0; k < cnt; ++k){
    int e = sorted_eid[e0 + k];
    if (t < 64) sbuf[t] = out[src[e]*64 + t];
    else if (t < 192) hbuf[t - 64] = hidden[(size_t)e*128 + (t - 64)];
    __syncthreads();
    float si = sbuf[i];
    #pragma unroll
    for (int j = 0; j < 32; ++j) acc[j] = fmaf(si, hbuf[h0 + j], acc[j]);
    if (t < 64) ssum += sbuf[t];
    __syncthreads();
  }
  short* row = (short*)Ksum + (size_t)blockIdx.x * KP;
  #pragma unroll
  for (int g = 0; g < 4; ++g){
    union { __hip_bfloat16 h[8]; short8_t v; } pk;
    #pragma unroll
    for (int j = 0; j < 8; ++j) pk.h[j] = __float2bfloat16(acc[g*8 + j]);
    *(short8_t*)(row + t*32 + g*8) = pk.v;
  }
  if (t < 64)
    ((__hip_bfloat16*)Ksum)[(size_t)blockIdx.x*KP + 8192 + t] = __float2bfloat16(ssum);
}

// ---------- agg GEMM: agg[c0+m][o] = sum_k Ksum[m][k] * W2t[o][k]  (bf16 MFMA) ----------
__global__ __launch_bounds__(256) void agg_gemm(const __hip_bfloat16* __restrict__ Ksum,
    const __hip_bfloat16* __restrict__ W2t, float* __restrict__ agg, int c0, int cn){
  __shared__ short As[64][64];
  __shared__ short Bs[64][64];
  int tid = threadIdx.x;
  int lane = tid & 63, wid = tid >> 6;
  int r = lane & 15, q = lane >> 4;
  int wm = (wid >> 1) * 32, wn = (wid & 1) * 32;
  int mbase = blockIdx.x * 64;
  f32x4_t z = {0.f, 0.f, 0.f, 0.f};
  f32x4_t acc00 = z, acc01 = z, acc10 = z, acc11 = z;
  const short* Kp = (const short*)Ksum;
  const short* Wp = (const short*)W2t;
  for (int kt = 0; kt < KP; kt += 64){
    #pragma unroll
    for (int l = 0; l < 2; ++l){
      int cid = tid + l*256;
      int row = cid >> 3, cc = cid & 7;
      int sc = cc ^ (row & 7);
      short8_t va = {0,0,0,0,0,0,0,0};
      int m = mbase + row;
      if (m < cn) va = *(const short8_t*)(Kp + (size_t)m*KP + kt + cc*8);
      *(short8_t*)&As[row][sc*8] = va;
      short8_t vb = *(const short8_t*)(Wp + (size_t)row*KP + kt + cc*8);
      *(short8_t*)&Bs[row][sc*8] = vb;
    }
    __syncthreads();
    #pragma unroll
    for (int ks = 0; ks < 2; ++ks){
      int kc = ks*4 + q;
      int sw = (kc ^ (r & 7)) * 8;
      short8_t a0 = *(const short8_t*)&As[wm + r][sw];
      short8_t a1 = *(const short8_t*)&As[wm + 16 + r][sw];
      short8_t b0 = *(const short8_t*)&Bs[wn + r][sw];
      short8_t b1 = *(const short8_t*)&Bs[wn + 16 + r][sw];
      acc00 = __builtin_amdgcn_mfma_f32_16x16x32_bf16(a0, b0, acc00, 0, 0, 0);
      acc01 = __builtin_amdgcn_mfma_f32_16x16x32_bf16(a0, b1, acc01, 0, 0, 0);
      acc10 = __builtin_amdgcn_mfma_f32_16x16x32_bf16(a1, b0, acc10, 0, 0, 0);
      acc11 = __builtin_amdgcn_mfma_f32_16x16x32_bf16(a1, b1, acc11, 0, 0, 0);
    }
    __syncthreads();
  }
  // C/D layout: col = lane&15, row = (lane>>4)*4 + reg
  #pragma unroll
  for (int reg = 0; reg < 4; ++reg){
    int m0 = mbase + wm + q*4 + reg;
    int m1 = m0 + 16;
    if (m0 < cn){
      agg[(size_t)(c0 + m0)*64 + wn + r]      = acc00[reg];
      agg[(size_t)(c0 + m0)*64 + wn + 16 + r] = acc01[reg];
    }
    if (m1 < cn){
      agg[(size_t)(c0 + m1)*64 + wn + r]      = acc10[reg];
      agg[(size_t)(c0 + m1)*64 + wn + 16 + r] = acc11[reg];
    }
  }
}

// ---------- fused fallback (only if workspace is tiny) ----------
__global__ void msg_fused_kernel(const float* __restrict__ hid, const float* __restrict__ w2,
                                 const float* __restrict__ b2, const float* __restrict__ out,
                                 const int* __restrict__ src, const int* __restrict__ dst,
                                 float* __restrict__ agg, int E){
  int e = blockIdx.x; int o = threadIdx.x;
  __shared__ float s[64];
  __shared__ float hsh[128];
  s[o] = out[src[e]*64 + o];
  hsh[o] = hid[(size_t)e*128 + o];
  hsh[64 + o] = hid[(size_t)e*128 + 64 + o];
  __syncthreads();
  float acc = 0.0f;
  for (int i = 0; i < 64; ++i){
    const float* wr = w2 + (size_t)(i*64 + o)*128;
    float wv = b2[i*64 + o];
    #pragma unroll 8
    for (int h = 0; h < 128; ++h) wv = fmaf(hsh[h], wr[h], wv);
    acc = fmaf(s[i], wv, acc);
  }
  atomicAdd(&agg[dst[e]*64 + o], acc);
}

// ---------- node update: m = relu(out@root_w + agg/deg + conv_b); GRU ----------
__global__ void node_kernel(const float* __restrict__ root_w, const float* __restrict__ conv_b,
                            const float* __restrict__ wih, const float* __restrict__ whh,
                            const float* __restrict__ bih, const float* __restrict__ bhh,
                            const float* __restrict__ agg, const int* __restrict__ counts,
                            float* __restrict__ out, int N){
  int n = blockIdx.x; int d = threadIdx.x;
  __shared__ float row[64];
  __shared__ float mrow[64];
  row[d] = out[n*64 + d];
  __syncthreads();
  float dv = fmaxf((float)counts[n], 1.0f);
  float acc = conv_b[d] + agg[n*64 + d] / dv;
  #pragma unroll 8
  for (int i = 0; i < 64; ++i) acc = fmaf(row[i], root_w[i*64 + d], acc);
  float m = fmaxf(acc, 0.0f);
  mrow[d] = m;
  __syncthreads();
  float gxr = bih[d], gxz = bih[64+d], gxn = bih[128+d];
  float ghr = bhh[d], ghz = bhh[64+d], ghn = bhh[128+d];
  #pragma unroll 4
  for (int k = 0; k < 64; ++k){
    float mk = mrow[k], hk = row[k];
    gxr = fmaf(mk, wih[d*64 + k], gxr);
    gxz = fmaf(mk, wih[(64+d)*64 + k], gxz);
    gxn = fmaf(mk, wih[(128+d)*64 + k], gxn);
    ghr = fmaf(hk, whh[d*64 + k], ghr);
    ghz = fmaf(hk, whh[(64+d)*64 + k], ghz);
    ghn = fmaf(hk, whh[(128+d)*64 + k], ghn);
  }
  float r = sigmoidf_(gxr + ghr);
  float z = sigmoidf_(gxz + ghz);
  float nn = tanhf(gxn + r*ghn);
  out[n*64 + d] = (1.0f - z)*nn + z*row[d];
}

// ---------- Set2Set LSTM step ----------
__global__ void lstm_kernel(const float* __restrict__ wih, const float* __restrict__ whh,
                            const float* __restrict__ bih, const float* __restrict__ bhh,
                            const float* __restrict__ qstar, float* __restrict__ hs,
                            float* __restrict__ cs, int B){
  int b = blockIdx.x; int t = threadIdx.x;   // 256 threads
  __shared__ float q[128];
  __shared__ float h[64];
  __shared__ float g[256];
  if (t < 128) q[t] = qstar[b*128 + t];
  if (t < 64)  h[t] = hs[b*64 + t];
  __syncthreads();
  float acc = bih[t] + bhh[t];
  #pragma unroll 8
  for (int k = 0; k < 128; ++k) acc = fmaf(q[k], wih[t*128 + k], acc);
  #pragma unroll 8
  for (int k = 0; k < 64;  ++k) acc = fmaf(h[k], whh[t*64 + k], acc);
  g[t] = acc;
  __syncthreads();
  if (t < 64){
    float ig = sigmoidf_(g[t]);
    float fg = sigmoidf_(g[64 + t]);
    float gg = tanhf(g[128 + t]);
    float og = sigmoidf_(g[192 + t]);
    float c = fg*cs[b*64 + t] + ig*gg;
    cs[b*64 + t] = c;
    hs[b*64 + t] = og*tanhf(c);
  }
}

// ---------- attention ----------
__global__ void attn_e_kernel(const float* __restrict__ out, const float* __restrict__ hs,
                              const int* __restrict__ batch, float* __restrict__ evals,
                              unsigned int* __restrict__ emaxk, int N){
  int n = blockIdx.x; int d = threadIdx.x;  // 64 = one wave
  int b = batch[n];
  float p = out[n*64 + d] * hs[b*64 + d];
  #pragma unroll
  for (int off = 32; off > 0; off >>= 1) p += __shfl_down(p, off, 64);
  if (d == 0){
    evals[n] = p;
    unsigned u = __float_as_uint(p);
    unsigned key = (u & 0x80000000u) ? ~u : (u | 0x80000000u);
    atomicMax(&emaxk[b], key);
  }
}

__global__ void attn_exp_kernel(const float* __restrict__ evals, const unsigned int* __restrict__ emaxk,
                                const int* __restrict__ batch, float* __restrict__ avals,
                                float* __restrict__ asum, int N){
  int n = blockIdx.x*blockDim.x + threadIdx.x;
  if (n >= N) return;
  int b = batch[n];
  unsigned key = emaxk[b];
  unsigned u = (key & 0x80000000u) ? (key ^ 0x80000000u) : ~key;
  float mx = __uint_as_float(u);
  float a = expf(evals[n] - mx);
  avals[n] = a;
  atomicAdd(&asum[b], a);
}

__global__ void attn_r_kernel(const float* __restrict__ out, const float* __restrict__ avals,
                              const float* __restrict__ asum, const int* __restrict__ batch,
                              float* __restrict__ rread, int N){
  int n = blockIdx.x; int d = threadIdx.x;
  int b = batch[n];
  float w = avals[n] / asum[b];
  atomicAdd(&rread[b*64 + d], w * out[n*64 + d]);
}

__global__ void qstar_kernel(const float* __restrict__ hs, const float* __restrict__ rread,
                             float* __restrict__ qstar, int B){
  int b = blockIdx.x; int t = threadIdx.x;  // 128
  qstar[b*128 + t] = (t < 64) ? hs[b*64 + t] : rread[b*64 + (t - 64)];
}

// ---------- readout ----------
__global__ void readout_kernel(const float* __restrict__ qstar, const float* __restrict__ w1,
                               const float* __restrict__ b1, const float* __restrict__ w2,
                               const float* __restrict__ b2, float* __restrict__ y, int B){
  int b = blockIdx.x; int t = threadIdx.x;   // 64
  __shared__ float q[128];
  q[t] = qstar[b*128 + t];
  q[64 + t] = qstar[b*128 + 64 + t];
  __syncthreads();
  float acc = b1[t];
  #pragma unroll 8
  for (int k = 0; k < 128; ++k) acc = fmaf(q[k], w1[t*128 + k], acc);
  float v = fmaxf(acc, 0.0f) * w2[t];
  #pragma unroll
  for (int off = 32; off > 0; off >>= 1) v += __shfl_down(v, off, 64);
  if (t == 0) y[b] = v + b2[0];
}

__global__ void copy_kernel(const float* __restrict__ in, float* __restrict__ dst, int n){
  int i = blockIdx.x*blockDim.x + threadIdx.x;
  if (i < n) dst[i] = in[i];
}

extern "C" void kernel_launch(void* const* d_in, const int* in_sizes, int n_in,
                              void* d_out, int out_size, void* d_ws, size_t ws_size,
                              hipStream_t stream){
  const float* x      = (const float*)d_in[0];
  const int*   ei     = (const int*)  d_in[1];
  const float* ea     = (const float*)d_in[2];
  const int*   batch  = (const int*)  d_in[3];
  const float* lin0_w = (const float*)d_in[4];
  const float* lin0_b = (const float*)d_in[5];
  const float* nn1_w  = (const float*)d_in[6];
  const float* nn1_b  = (const float*)d_in[7];
  const float* nn2_w  = (const float*)d_in[8];
  const float* nn2_b  = (const float*)d_in[9];
  const float* root_w = (const float*)d_in[10];
  const float* conv_b = (const float*)d_in[11];
  const float* gwih   = (const float*)d_in[12];
  const float* gwhh   = (const float*)d_in[13];
  const float* gbih   = (const float*)d_in[14];
  const float* gbhh   = (const float*)d_in[15];
  const float* lwih   = (const float*)d_in[16];
  const float* lwhh   = (const float*)d_in[17];
  const float* lbih   = (const float*)d_in[18];
  const float* lbhh   = (const float*)d_in[19];
  const float* l1w    = (const float*)d_in[20];
  const float* l1b    = (const float*)d_in[21];
  const float* l2w    = (const float*)d_in[22];
  const float* l2b    = (const float*)d_in[23];

  const int N = in_sizes[0] / 14;
  const int E = in_sizes[1] / 2;
  const int B = NBG;
  const int* src  = ei;
  const int* dstv = ei + E;

  char* wsp = (char*)d_ws; size_t off = 0;
  auto alloc = [&](size_t bytes)->char* {
    char* p = wsp + off; off += (bytes + 255) & ~((size_t)255); return p;
  };
  float* out    = (float*)alloc((size_t)N*64*4);
  float* agg    = (float*)alloc((size_t)N*64*4);
  int*   counts = (int*)  alloc((size_t)N*4);
  int*   starts = (int*)  alloc((size_t)N*4);
  int*   cursor = (int*)  alloc((size_t)N*4);
  int*   sorted = (int*)  alloc((size_t)E*4);
  float* evals  = (float*)alloc((size_t)N*4);
  float* avals  = (float*)alloc((size_t)N*4);
  float* qstar  = (float*)alloc((size_t)B*128*4);
  float* hs     = (float*)alloc((size_t)B*64*4);
  float* cs     = (float*)alloc((size_t)B*64*4);
  float* rread  = (float*)alloc((size_t)B*64*4);
  float* asum   = (float*)alloc((size_t)B*4);
  unsigned int* emaxk = (unsigned int*)alloc((size_t)B*4);
  float* hidden = (float*)alloc((size_t)E*128*4);
  __hip_bfloat16* W2t = (__hip_bfloat16*)alloc((size_t)64*KP*2);

  size_t rem = (ws_size > off) ? (ws_size - off) : 0;
  long cap = (long)(rem / ((size_t)KP*2));
  int chunk = (cap < (long)N) ? (int)cap : N;
  bool useK = chunk >= 64;
  __hip_bfloat16* Ksum = nullptr;
  if (useK) Ksum = (__hip_bfloat16*)alloc((size_t)chunk*KP*2);

  lin0_kernel<<<N, 64, 0, stream>>>(x, lin0_w, lin0_b, out, N);
  ehid_kernel<<<E, 128, 0, stream>>>(ea, nn1_w, nn1_b, hidden, E);
  hipMemsetAsync(counts, 0, (size_t)N*4, stream);
  count_kernel<<<(E + 255)/256, 256, 0, stream>>>(dstv, counts, E);
  if (useK){
    scan_kernel<<<1, 1024, 0, stream>>>(counts, starts, cursor, N);
    scatter_kernel<<<(E + 255)/256, 256, 0, stream>>>(dstv, cursor, sorted, E);
    w2t_build<<<64, 256, 0, stream>>>(nn2_w, nn2_b, W2t);
  }

  for (int it = 0; it < 3; ++it){
    if (useK){
      for (int c0 = 0; c0 < N; c0 += chunk){
        int cn = (N - c0 < chunk) ? (N - c0) : chunk;
        ksum_build<<<cn, 256, 0, stream>>>(out, hidden, sorted, starts, counts, src, Ksum, c0);
        agg_gemm<<<(cn + 63)/64, 256, 0, stream>>>(Ksum, W2t, agg, c0, cn);
      }
    } else {
      hipMemsetAsync(agg, 0, (size_t)N*64*4, stream);
      msg_fused_kernel<<<E, 64, 0, stream>>>(hidden, nn2_w, nn2_b, out, src, dstv, agg, E);
    }
    node_kernel<<<N, 64, 0, stream>>>(root_w, conv_b, gwih, gwhh, gbih, gbhh, agg, counts, out, N);
  }

  hipMemsetAsync(qstar, 0, (size_t)B*128*4, stream);
  hipMemsetAsync(hs, 0, (size_t)B*64*4, stream);
  hipMemsetAsync(cs, 0, (size_t)B*64*4, stream);
  for (int s = 0; s < 3; ++s){
    lstm_kernel<<<B, 256, 0, stream>>>(lwih, lwhh, lbih, lbhh, qstar, hs, cs, B);
    hipMemsetAsync(emaxk, 0, (size_t)B*4, stream);
    hipMemsetAsync(asum, 0, (size_t)B*4, stream);
    hipMemsetAsync(rread, 0, (size_t)B*64*4, stream);
    attn_e_kernel<<<N, 64, 0, stream>>>(out, hs, batch, evals, emaxk, N);
    attn_exp_kernel<<<(N + 255)/256, 256, 0, stream>>>(evals, emaxk, batch, avals, asum, N);
    attn_r_kernel<<<N, 64, 0, stream>>>(out, avals, asum, batch, rread, N);
    qstar_kernel<<<B, 128, 0, stream>>>(hs, rread, qstar, B);
  }

  readout_kernel<<<B, 64, 0, stream>>>(qstar, l1w, l1b, l2w, l2b, (float*)d_out, B);
  copy_kernel<<<((size_t)N*64 + 255)/256, 256, 0, stream>>>(out, (float*)d_out + 300, N*64);
}

// Round 3
// 659.696 us; speedup vs baseline: 49.2812x; 2.3051x over previous
//
#include <hip/hip_runtime.h>
#include <math.h>

#define NBG 300
#define KP 8256   // K = 64*128 (i,h) + 64 bias rows

typedef __attribute__((ext_vector_type(8))) short short8_t;
typedef __attribute__((ext_vector_type(4))) float f32x4_t;

#define MFMA16(a,b,c) __builtin_amdgcn_mfma_f32_16x16x32_bf16(a,b,c,0,0,0)

__device__ __forceinline__ float sigmoidf_(float x){ return 1.0f/(1.0f+expf(-x)); }
__device__ __forceinline__ float bf2f(short s){
  union{unsigned u; float f;} v; v.u = ((unsigned)(unsigned short)s) << 16; return v.f;
}
__device__ __forceinline__ short f2bf(float f){
  union{float f; unsigned u;} v; v.f = f;
  unsigned r = (v.u + 0x7fffu + ((v.u >> 16) & 1u)) >> 16;
  return (short)r;
}

// ---------- lin0: out = relu(x @ lin0_w.T + b); writes f32 + bf16 ----------
__global__ void lin0_kernel(const float* __restrict__ x, const float* __restrict__ w,
                            const float* __restrict__ b, float* __restrict__ out,
                            short* __restrict__ out_bf, int N){
  int n = blockIdx.x; int d = threadIdx.x;
  __shared__ float xs[16];
  if (d < 14) xs[d] = x[n*14 + d];
  __syncthreads();
  float acc = b[d];
  #pragma unroll
  for (int k = 0; k < 14; ++k) acc = fmaf(xs[k], w[d*14 + k], acc);
  float v = fmaxf(acc, 0.0f);
  out[n*64 + d] = v;
  out_bf[n*64 + d] = f2bf(v);
}

// ---------- edge MLP hidden (bf16 out) ----------
__global__ void ehid_kernel(const float* __restrict__ ea, const float* __restrict__ w,
                            const float* __restrict__ b, short* __restrict__ hid_bf, int E){
  int e = blockIdx.x; int t = threadIdx.x;
  __shared__ float as[4];
  if (t < 4) as[t] = ea[e*4 + t];
  __syncthreads();
  float acc = b[t];
  #pragma unroll
  for (int k = 0; k < 4; ++k) acc = fmaf(as[k], w[t*4 + k], acc);
  hid_bf[(size_t)e*128 + t] = f2bf(fmaxf(acc, 0.0f));
}

// ---------- counting sort infra ----------
__global__ void count_kernel(const int* __restrict__ idx, int* __restrict__ counts, int len){
  int e = blockIdx.x*blockDim.x + threadIdx.x;
  if (e < len) atomicAdd(&counts[idx[e]], 1);
}

__global__ __launch_bounds__(1024) void scan_kernel(const int* __restrict__ counts,
    int* __restrict__ starts, int* __restrict__ cursor, int N){
  __shared__ int part[1024];
  int t = threadIdx.x;
  int per = (N + 1023) >> 10;
  int base = t * per;
  int s = 0;
  for (int j = 0; j < per; ++j){ int idx = base + j; if (idx < N) s += counts[idx]; }
  part[t] = s;
  __syncthreads();
  for (int off = 1; off < 1024; off <<= 1){
    int v = (t >= off) ? part[t - off] : 0;
    __syncthreads();
    part[t] += v;
    __syncthreads();
  }
  int run = (t == 0) ? 0 : part[t-1];
  for (int j = 0; j < per; ++j){
    int idx = base + j;
    if (idx < N){ starts[idx] = run; cursor[idx] = run; run += counts[idx]; }
  }
}

__global__ void scatter_kernel(const int* __restrict__ dst, int* __restrict__ cursor,
                               int* __restrict__ sorted_eid, int E){
  int e = blockIdx.x*blockDim.x + threadIdx.x;
  if (e < E){ int p = atomicAdd(&cursor[dst[e]], 1); sorted_eid[p] = e; }
}

// ---------- W2t build: W2t[o][i*128+h] = w2[(i*64+o)][h]; W2t[o][8192+i] = b2[i*64+o] ----------
__global__ void w2t_build(const float* __restrict__ w2, const float* __restrict__ b2,
                          short* __restrict__ W2t){
  int o = blockIdx.x;
  for (int k = threadIdx.x; k < KP; k += blockDim.x){
    float val;
    if (k < 8192){ int i = k >> 7, h = k & 127; val = w2[(size_t)(i*64 + o)*128 + h]; }
    else val = b2[(k - 8192)*64 + o];
    W2t[(size_t)o*KP + k] = f2bf(val);
  }
}

// ---------- fused message GEMM + scatter ----------
// msg[e,o] = sum_{i,h} out[src[e],i]*hid[e,h]*w2[(i*64+o),h] + sum_i out[src[e],i]*b2[i*64+o]
// A built on the fly (hid row in regs); B = W2t (L2-resident); atomicAdd to agg[dst].
__global__ __launch_bounds__(256) void msg_gemm(
    const short* __restrict__ out_bf, const short* __restrict__ hid_bf,
    const short* __restrict__ W2t, const int* __restrict__ sorted,
    const int* __restrict__ src, const int* __restrict__ dstv,
    float* __restrict__ agg, int E)
{
  __shared__ float src_sf[64][68];
  __shared__ short As[64*64];
  __shared__ short Bs[64*64];
  __shared__ int   dst_s[64];
  __shared__ int   eid_s[64];

  int tid = threadIdx.x;
  int blk = blockIdx.x;

  if (tid < 64){
    int p = blk*64 + tid;
    int e = (p < E) ? sorted[p] : -1;
    eid_s[tid] = e;
    dst_s[tid] = (e >= 0) ? dstv[e] : -1;
  }
  __syncthreads();

  int er = tid >> 2, kq = tid & 3;
  int e = eid_s[er];

  // hid row chunk (this thread's 32 h-columns) into registers, f32
  float h_lo[16], h_hi[16];
  {
    short8_t hv0 = {0,0,0,0,0,0,0,0}, hv1 = hv0, hv2 = hv0, hv3 = hv0;
    if (e >= 0){
      const short* hp = hid_bf + (size_t)e*128;
      hv0 = *(const short8_t*)(hp + kq*16);
      hv1 = *(const short8_t*)(hp + kq*16 + 8);
      hv2 = *(const short8_t*)(hp + 64 + kq*16);
      hv3 = *(const short8_t*)(hp + 64 + kq*16 + 8);
    }
    #pragma unroll
    for (int j = 0; j < 8; ++j){
      h_lo[j]     = bf2f(hv0[j]);
      h_lo[8 + j] = bf2f(hv1[j]);
      h_hi[j]     = bf2f(hv2[j]);
      h_hi[8 + j] = bf2f(hv3[j]);
    }
  }
  // src row (64 values) into LDS f32 (padded 68: bank-spread, aligned)
  {
    short8_t s0 = {0,0,0,0,0,0,0,0}, s1 = s0;
    if (e >= 0){
      int s = src[e];
      const short* sp = out_bf + (size_t)s*64;
      s0 = *(const short8_t*)(sp + kq*16);
      s1 = *(const short8_t*)(sp + kq*16 + 8);
    }
    #pragma unroll
    for (int j = 0; j < 8; ++j){
      src_sf[er][kq*16 + j]     = bf2f(s0[j]);
      src_sf[er][kq*16 + 8 + j] = bf2f(s1[j]);
    }
  }
  __syncthreads();

  int lane = tid & 63, wid = tid >> 6;
  int r = lane & 15, q4 = lane >> 4;
  int mh = (wid >> 1)*32, nh = (wid & 1)*32;
  f32x4_t z4 = {0.f,0.f,0.f,0.f};
  f32x4_t acc00 = z4, acc01 = z4, acc10 = z4, acc11 = z4;

  for (int tt = 0; tt < 129; ++tt){
    // ---- build A tile (64 edges x 64 k) ----
    {
      float prod[16];
      if (tt < 128){
        float s = src_sf[er][tt >> 1];
        if (tt & 1){
          #pragma unroll
          for (int j = 0; j < 16; ++j) prod[j] = s * h_hi[j];
        } else {
          #pragma unroll
          for (int j = 0; j < 16; ++j) prod[j] = s * h_lo[j];
        }
      } else {
        #pragma unroll
        for (int j = 0; j < 16; ++j) prod[j] = src_sf[er][kq*16 + j];
      }
      short pk[16];
      #pragma unroll
      for (int j = 0; j < 16; ++j) pk[j] = f2bf(prod[j]);
      *(short8_t*)(As + er*64 + (((kq*2)   ^ (er & 7))*8)) = *(short8_t*)&pk[0];
      *(short8_t*)(As + er*64 + (((kq*2+1) ^ (er & 7))*8)) = *(short8_t*)&pk[8];
    }
    // ---- stage B tile from W2t ----
    {
      int o = tid >> 2, cq = tid & 3;
      const short* wrow = W2t + (size_t)o*KP + tt*64 + cq*16;
      short8_t b0 = *(const short8_t*)(wrow);
      short8_t b1 = *(const short8_t*)(wrow + 8);
      *(short8_t*)(Bs + o*64 + (((cq*2)   ^ (o & 7))*8)) = b0;
      *(short8_t*)(Bs + o*64 + (((cq*2+1) ^ (o & 7))*8)) = b1;
    }
    __syncthreads();
    #pragma unroll
    for (int ks = 0; ks < 2; ++ks){
      int sw = ((ks*4 + q4) ^ (r & 7))*8;
      short8_t a0 = *(const short8_t*)(As + (mh + r)*64 + sw);
      short8_t a1 = *(const short8_t*)(As + (mh + 16 + r)*64 + sw);
      short8_t b0 = *(const short8_t*)(Bs + (nh + r)*64 + sw);
      short8_t b1 = *(const short8_t*)(Bs + (nh + 16 + r)*64 + sw);
      acc00 = MFMA16(a0, b0, acc00);
      acc01 = MFMA16(a0, b1, acc01);
      acc10 = MFMA16(a1, b0, acc10);
      acc11 = MFMA16(a1, b1, acc11);
    }
    __syncthreads();
  }

  // ---- scatter: C[e_local][o] -> atomicAdd agg[dst[e]*64+o] ----
  #pragma unroll
  for (int reg = 0; reg < 4; ++reg){
    int e0 = mh + q4*4 + reg;
    int e1 = e0 + 16;
    int o0 = nh + r, o1 = nh + 16 + r;
    int d0 = dst_s[e0], d1 = dst_s[e1];
    if (d0 >= 0){
      atomicAdd(&agg[(size_t)d0*64 + o0], acc00[reg]);
      atomicAdd(&agg[(size_t)d0*64 + o1], acc01[reg]);
    }
    if (d1 >= 0){
      atomicAdd(&agg[(size_t)d1*64 + o0], acc10[reg]);
      atomicAdd(&agg[(size_t)d1*64 + o1], acc11[reg]);
    }
  }
}

// ---------- node update (MFMA): M = relu(H@root_w + agg/deg + cb); GRU ----------
__global__ __launch_bounds__(256) void node_mfma(
    const short* __restrict__ out_bf, const float* __restrict__ agg,
    const int* __restrict__ counts,
    const float* __restrict__ root_w, const float* __restrict__ conv_b,
    const float* __restrict__ gwih, const float* __restrict__ gwhh,
    const float* __restrict__ gbih, const float* __restrict__ gbhh,
    float* __restrict__ out, short* __restrict__ out_bf_w, int N)
{
  __shared__ short XH[64*128];      // cols 0..63: M (after stage1), 64..127: H
  __shared__ short rootT[64*64];    // [d][i]
  __shared__ short Wih_s[192*64];   // [g][k]
  __shared__ short Whh_s[192*64];
  __shared__ float rdeg_s[64];
  __shared__ float cb_s[64];

  int tid = threadIdx.x;
  int blk = blockIdx.x;
  int nbase = blk*64;

  // stage H (right half of XH) from out_bf
  {
    int n = tid >> 2, cq = tid & 3;
    int ng = nbase + n;
    short8_t v0 = {0,0,0,0,0,0,0,0}, v1 = v0;
    if (ng < N){
      const short* p = out_bf + (size_t)ng*64;
      v0 = *(const short8_t*)(p + cq*16);
      v1 = *(const short8_t*)(p + cq*16 + 8);
    }
    int c0 = 8 + cq*2;
    *(short8_t*)(XH + n*128 + ((c0     ^ (n & 7))*8)) = v0;
    *(short8_t*)(XH + n*128 + (((c0+1) ^ (n & 7))*8)) = v1;
  }
  // stage rootT (transposed)
  {
    int i = tid >> 2, dq = tid & 3;
    #pragma unroll
    for (int j = 0; j < 16; ++j){
      int d = dq*16 + j;
      short v = f2bf(root_w[i*64 + d]);
      rootT[d*64 + (((i >> 3) ^ (d & 7))*8) + (i & 7)] = v;
    }
  }
  // stage Wih/Whh rows
  if (tid < 192){
    int g = tid;
    short pk[8];
    #pragma unroll
    for (int c = 0; c < 8; ++c){
      #pragma unroll
      for (int j = 0; j < 8; ++j) pk[j] = f2bf(gwih[g*64 + c*8 + j]);
      *(short8_t*)(Wih_s + g*64 + ((c ^ (g & 7))*8)) = *(short8_t*)&pk[0];
    }
    #pragma unroll
    for (int c = 0; c < 8; ++c){
      #pragma unroll
      for (int j = 0; j < 8; ++j) pk[j] = f2bf(gwhh[g*64 + c*8 + j]);
      *(short8_t*)(Whh_s + g*64 + ((c ^ (g & 7))*8)) = *(short8_t*)&pk[0];
    }
  }
  if (tid < 64){
    int ng = nbase + tid;
    int c = (ng < N) ? counts[ng] : 1;
    rdeg_s[tid] = 1.0f / fmaxf((float)c, 1.0f);
    cb_s[tid] = conv_b[tid];
  }
  __syncthreads();

  int lane = tid & 63, wid = tid >> 6;
  int r = lane & 15, q4 = lane >> 4;

  // ---- stage1: C1[n][d] = sum_i H[n][i]*rootT[d][i] ----
  {
    int mh = (wid >> 1)*32, nh = (wid & 1)*32;
    f32x4_t z4 = {0.f,0.f,0.f,0.f};
    f32x4_t c00 = z4, c01 = z4, c10 = z4, c11 = z4;
    #pragma unroll
    for (int ks = 0; ks < 2; ++ks){
      int ck = 8 + ks*4 + q4;           // H half
      int swA = (ck ^ (r & 7))*8;
      int swB = ((ks*4 + q4) ^ (r & 7))*8;
      short8_t a0 = *(const short8_t*)(XH + (mh + r)*128 + swA);
      short8_t a1 = *(const short8_t*)(XH + (mh + 16 + r)*128 + swA);
      short8_t b0 = *(const short8_t*)(rootT + (nh + r)*64 + swB);
      short8_t b1 = *(const short8_t*)(rootT + (nh + 16 + r)*64 + swB);
      c00 = MFMA16(a0, b0, c00);
      c01 = MFMA16(a0, b1, c01);
      c10 = MFMA16(a1, b0, c10);
      c11 = MFMA16(a1, b1, c11);
    }
    // epilogue: += agg/deg + cb, relu, write bf16 into XH left half
    #pragma unroll
    for (int mm = 0; mm < 2; ++mm){
      #pragma unroll
      for (int nn = 0; nn < 2; ++nn){
        f32x4_t cc = mm == 0 ? (nn == 0 ? c00 : c01) : (nn == 0 ? c10 : c11);
        int d = nh + nn*16 + r;
        #pragma unroll
        for (int reg = 0; reg < 4; ++reg){
          int n = mh + mm*16 + q4*4 + reg;
          int ng = nbase + n;
          float av = (ng < N) ? agg[(size_t)ng*64 + d] : 0.0f;
          float v = cc[reg] + av * rdeg_s[n] + cb_s[d];
          v = fmaxf(v, 0.0f);
          XH[n*128 + (((d >> 3) ^ (n & 7))*8) + (d & 7)] = f2bf(v);
        }
      }
    }
  }
  __syncthreads();

  // ---- stage2: gx[n][g] = M@Wih, gh[n][g] = H@Whh; wave wid owns d-cols wid*16..+15 ----
  f32x4_t ax[4][3], ah[4][3];
  {
    f32x4_t z4 = {0.f,0.f,0.f,0.f};
    #pragma unroll
    for (int mt = 0; mt < 4; ++mt)
      #pragma unroll
      for (int gt = 0; gt < 3; ++gt){ ax[mt][gt] = z4; ah[mt][gt] = z4; }
  }
  #pragma unroll
  for (int ks = 0; ks < 2; ++ks){
    int ckM = ks*4 + q4;
    int ckH = 8 + ks*4 + q4;
    int swM = (ckM ^ (r & 7))*8;
    int swH = (ckH ^ (r & 7))*8;
    int swB = ((ks*4 + q4) ^ (r & 7))*8;
    short8_t bx[3], bh[3];
    #pragma unroll
    for (int gt = 0; gt < 3; ++gt){
      int g = gt*64 + wid*16 + r;
      bx[gt] = *(const short8_t*)(Wih_s + g*64 + swB);
      bh[gt] = *(const short8_t*)(Whh_s + g*64 + swB);
    }
    #pragma unroll
    for (int mt = 0; mt < 4; ++mt){
      short8_t aM = *(const short8_t*)(XH + (mt*16 + r)*128 + swM);
      short8_t aH = *(const short8_t*)(XH + (mt*16 + r)*128 + swH);
      #pragma unroll
      for (int gt = 0; gt < 3; ++gt){
        ax[mt][gt] = MFMA16(aM, bx[gt], ax[mt][gt]);
        ah[mt][gt] = MFMA16(aH, bh[gt], ah[mt][gt]);
      }
    }
  }

  // ---- GRU epilogue (all values for (n,d) in-lane) ----
  {
    int d = wid*16 + r;
    float bir = gbih[d],      bhr = gbhh[d];
    float biz = gbih[64 + d], bhz = gbhh[64 + d];
    float bin_ = gbih[128 + d], bhn = gbhh[128 + d];
    #pragma unroll
    for (int mt = 0; mt < 4; ++mt){
      #pragma unroll
      for (int reg = 0; reg < 4; ++reg){
        int n = mt*16 + q4*4 + reg;
        int ng = nbase + n;
        if (ng < N){
          float gxr = ax[mt][0][reg], gxz = ax[mt][1][reg], gxn = ax[mt][2][reg];
          float ghr = ah[mt][0][reg], ghz = ah[mt][1][reg], ghn = ah[mt][2][reg];
          float rr = sigmoidf_(gxr + ghr + bir + bhr);
          float zz = sigmoidf_(gxz + ghz + biz + bhz);
          float nn = tanhf(gxn + bin_ + rr*(ghn + bhn));
          float h = out[(size_t)ng*64 + d];
          float v = (1.0f - zz)*nn + zz*h;
          out[(size_t)ng*64 + d] = v;
          out_bf_w[(size_t)ng*64 + d] = f2bf(v);
        }
      }
    }
  }
}

// ---------- Set2Set (3 steps) + readout, one kernel, 1 block per graph ----------
__global__ __launch_bounds__(64) void set2set_kernel(
    const float* __restrict__ out, const int* __restrict__ bstarts,
    const int* __restrict__ bcounts,
    const float* __restrict__ lwih, const float* __restrict__ lwhh,
    const float* __restrict__ lbih, const float* __restrict__ lbhh,
    const float* __restrict__ l1w, const float* __restrict__ l1b,
    const float* __restrict__ l2w, const float* __restrict__ l2b,
    float* __restrict__ y)
{
  int b = blockIdx.x, d = threadIdx.x;
  __shared__ float qs[128];
  __shared__ float hsl[64];
  __shared__ float ev[2048];
  int s0 = bstarts[b], cnt = bcounts[b];
  if (cnt > 2048) cnt = 2048;
  float hs = 0.f, cs = 0.f;
  qs[d] = 0.f; qs[64 + d] = 0.f;
  __syncthreads();

  for (int step = 0; step < 3; ++step){
    hsl[d] = hs;
    __syncthreads();
    float g[4];
    #pragma unroll
    for (int gg = 0; gg < 4; ++gg){
      int grow = gg*64 + d;
      float a = lbih[grow] + lbhh[grow];
      const float* wi = lwih + grow*128;
      #pragma unroll 8
      for (int k = 0; k < 128; ++k) a = fmaf(qs[k], wi[k], a);
      const float* wh = lwhh + grow*64;
      #pragma unroll 8
      for (int k = 0; k < 64; ++k) a = fmaf(hsl[k], wh[k], a);
      g[gg] = a;
    }
    float ig = sigmoidf_(g[0]);
    float fg = sigmoidf_(g[1]);
    float gg2 = tanhf(g[2]);
    float og = sigmoidf_(g[3]);
    cs = fg*cs + ig*gg2;
    hs = og*tanhf(cs);
    __syncthreads();

    // attention: e_n = dot(out[n], hs)
    float m = -1e30f;
    for (int idx = 0; idx < cnt; ++idx){
      float p = out[(size_t)(s0 + idx)*64 + d] * hs;
      #pragma unroll
      for (int off = 32; off > 0; off >>= 1) p += __shfl_xor(p, off, 64);
      if (d == 0) ev[idx] = p;
      m = fmaxf(m, p);
    }
    __syncthreads();
    float ls = 0.f;
    for (int idx = d; idx < cnt; idx += 64){
      float a = expf(ev[idx] - m);
      ev[idx] = a;
      ls += a;
    }
    #pragma unroll
    for (int off = 32; off > 0; off >>= 1) ls += __shfl_xor(ls, off, 64);
    __syncthreads();
    float rr = 0.f;
    for (int idx = 0; idx < cnt; ++idx)
      rr = fmaf(ev[idx], out[(size_t)(s0 + idx)*64 + d], rr);
    rr /= ls;
    qs[d] = hs;
    qs[64 + d] = rr;
    __syncthreads();
  }

  // readout
  float acc = l1b[d];
  const float* w1 = l1w + d*128;
  #pragma unroll 8
  for (int k = 0; k < 128; ++k) acc = fmaf(qs[k], w1[k], acc);
  float v = fmaxf(acc, 0.0f) * l2w[d];
  #pragma unroll
  for (int off = 32; off > 0; off >>= 1) v += __shfl_xor(v, off, 64);
  if (d == 0) y[b] = v + l2b[0];
}

__global__ void copy_kernel(const float* __restrict__ in, float* __restrict__ dst, int n){
  int i = blockIdx.x*blockDim.x + threadIdx.x;
  if (i < n) dst[i] = in[i];
}

extern "C" void kernel_launch(void* const* d_in, const int* in_sizes, int n_in,
                              void* d_out, int out_size, void* d_ws, size_t ws_size,
                              hipStream_t stream){
  const float* x      = (const float*)d_in[0];
  const int*   ei     = (const int*)  d_in[1];
  const float* ea     = (const float*)d_in[2];
  const int*   batch  = (const int*)  d_in[3];
  const float* lin0_w = (const float*)d_in[4];
  const float* lin0_b = (const float*)d_in[5];
  const float* nn1_w  = (const float*)d_in[6];
  const float* nn1_b  = (const float*)d_in[7];
  const float* nn2_w  = (const float*)d_in[8];
  const float* nn2_b  = (const float*)d_in[9];
  const float* root_w = (const float*)d_in[10];
  const float* conv_b = (const float*)d_in[11];
  const float* gwih   = (const float*)d_in[12];
  const float* gwhh   = (const float*)d_in[13];
  const float* gbih   = (const float*)d_in[14];
  const float* gbhh   = (const float*)d_in[15];
  const float* lwih   = (const float*)d_in[16];
  const float* lwhh   = (const float*)d_in[17];
  const float* lbih   = (const float*)d_in[18];
  const float* lbhh   = (const float*)d_in[19];
  const float* l1w    = (const float*)d_in[20];
  const float* l1b    = (const float*)d_in[21];
  const float* l2w    = (const float*)d_in[22];
  const float* l2b    = (const float*)d_in[23];

  const int N = in_sizes[0] / 14;
  const int E = in_sizes[1] / 2;
  const int B = NBG;
  const int* src  = ei;
  const int* dstv = ei + E;

  char* wsp = (char*)d_ws; size_t off = 0;
  auto alloc = [&](size_t bytes)->char* {
    char* p = wsp + off; off += (bytes + 255) & ~((size_t)255); return p;
  };
  float* out     = (float*)alloc((size_t)N*64*4);
  short* out_bf  = (short*)alloc((size_t)N*64*2);
  float* agg     = (float*)alloc((size_t)N*64*4);
  int*   counts  = (int*)  alloc((size_t)N*4);
  int*   starts  = (int*)  alloc((size_t)N*4);
  int*   cursor  = (int*)  alloc((size_t)N*4);
  int*   sorted  = (int*)  alloc((size_t)E*4);
  int*   bcounts = (int*)  alloc((size_t)B*4);
  int*   bstarts = (int*)  alloc((size_t)B*4);
  int*   bcursor = (int*)  alloc((size_t)B*4);
  short* hid_bf  = (short*)alloc((size_t)E*128*2);
  short* W2t     = (short*)alloc((size_t)64*KP*2);

  lin0_kernel<<<N, 64, 0, stream>>>(x, lin0_w, lin0_b, out, out_bf, N);
  ehid_kernel<<<E, 128, 0, stream>>>(ea, nn1_w, nn1_b, hid_bf, E);

  hipMemsetAsync(counts, 0, (size_t)N*4, stream);
  count_kernel<<<(E + 255)/256, 256, 0, stream>>>(dstv, counts, E);
  scan_kernel<<<1, 1024, 0, stream>>>(counts, starts, cursor, N);
  scatter_kernel<<<(E + 255)/256, 256, 0, stream>>>(dstv, cursor, sorted, E);

  hipMemsetAsync(bcounts, 0, (size_t)B*4, stream);
  count_kernel<<<(N + 255)/256, 256, 0, stream>>>(batch, bcounts, N);
  scan_kernel<<<1, 1024, 0, stream>>>(bcounts, bstarts, bcursor, B);

  w2t_build<<<64, 256, 0, stream>>>(nn2_w, nn2_b, W2t);

  int mblocks = (E + 63)/64;
  int nblocks = (N + 63)/64;
  for (int it = 0; it < 3; ++it){
    hipMemsetAsync(agg, 0, (size_t)N*64*4, stream);
    msg_gemm<<<mblocks, 256, 0, stream>>>(out_bf, hid_bf, W2t, sorted, src, dstv, agg, E);
    node_mfma<<<nblocks, 256, 0, stream>>>(out_bf, agg, counts, root_w, conv_b,
                                           gwih, gwhh, gbih, gbhh, out, out_bf, N);
  }

  set2set_kernel<<<B, 64, 0, stream>>>(out, bstarts, bcounts, lwih, lwhh, lbih, lbhh,
                                       l1w, l1b, l2w, l2b, (float*)d_out);
  copy_kernel<<<((size_t)N*64 + 255)/256, 256, 0, stream>>>(out, (float*)d_out + 300, N*64);
}

// Round 5
// 458.657 us; speedup vs baseline: 70.8822x; 1.4383x over previous
//
#include <hip/hip_runtime.h>
#include <math.h>

#define NBG 300
#define KP 8256   // K = 64*128 (i,h) + 64 bias rows

typedef __attribute__((ext_vector_type(8))) short short8_t;
typedef __attribute__((ext_vector_type(4))) float f32x4_t;

#define MFMA16(a,b,c) __builtin_amdgcn_mfma_f32_16x16x32_bf16(a,b,c,0,0,0)

__device__ __forceinline__ float sigmoidf_(float x){ return 1.0f/(1.0f+expf(-x)); }
__device__ __forceinline__ float bf2f(short s){
  union{unsigned u; float f;} v; v.u = ((unsigned)(unsigned short)s) << 16; return v.f;
}
__device__ __forceinline__ short f2bf(float f){
  union{float f; unsigned u;} v; v.f = f;
  unsigned r = (v.u + 0x7fffu + ((v.u >> 16) & 1u)) >> 16;
  return (short)r;
}
__device__ __forceinline__ unsigned cvt_pk_bf16(float lo, float hi){
  unsigned r;
  asm volatile("v_cvt_pk_bf16_f32 %0, %1, %2" : "=v"(r) : "v"(lo), "v"(hi));
  return r;
}
union FragA { short8_t v; unsigned u[4]; };

// ---------- lin0 ----------
__global__ void lin0_kernel(const float* __restrict__ x, const float* __restrict__ w,
                            const float* __restrict__ b, float* __restrict__ out,
                            short* __restrict__ out_bf, int N){
  int n = blockIdx.x; int d = threadIdx.x;
  __shared__ float xs[16];
  if (d < 14) xs[d] = x[n*14 + d];
  __syncthreads();
  float acc = b[d];
  #pragma unroll
  for (int k = 0; k < 14; ++k) acc = fmaf(xs[k], w[d*14 + k], acc);
  float v = fmaxf(acc, 0.0f);
  out[n*64 + d] = v;
  out_bf[n*64 + d] = f2bf(v);
}

// ---------- edge MLP hidden (bf16 out) ----------
__global__ void ehid_kernel(const float* __restrict__ ea, const float* __restrict__ w,
                            const float* __restrict__ b, short* __restrict__ hid_bf, int E){
  int e = blockIdx.x; int t = threadIdx.x;
  __shared__ float as[4];
  if (t < 4) as[t] = ea[e*4 + t];
  __syncthreads();
  float acc = b[t];
  #pragma unroll
  for (int k = 0; k < 4; ++k) acc = fmaf(as[k], w[t*4 + k], acc);
  hid_bf[(size_t)e*128 + t] = f2bf(fmaxf(acc, 0.0f));
}

// ---------- counting sort infra ----------
__global__ void count_kernel(const int* __restrict__ idx, int* __restrict__ counts, int len){
  int e = blockIdx.x*blockDim.x + threadIdx.x;
  if (e < len) atomicAdd(&counts[idx[e]], 1);
}

__global__ __launch_bounds__(1024) void scan_kernel(const int* __restrict__ counts,
    int* __restrict__ starts, int* __restrict__ cursor, int N){
  __shared__ int part[1024];
  int t = threadIdx.x;
  int per = (N + 1023) >> 10;
  int base = t * per;
  int s = 0;
  for (int j = 0; j < per; ++j){ int idx = base + j; if (idx < N) s += counts[idx]; }
  part[t] = s;
  __syncthreads();
  for (int off = 1; off < 1024; off <<= 1){
    int v = (t >= off) ? part[t - off] : 0;
    __syncthreads();
    part[t] += v;
    __syncthreads();
  }
  int run = (t == 0) ? 0 : part[t-1];
  for (int j = 0; j < per; ++j){
    int idx = base + j;
    if (idx < N){ starts[idx] = run; cursor[idx] = run; run += counts[idx]; }
  }
}

__global__ void scatter_kernel(const int* __restrict__ dst, int* __restrict__ cursor,
                               int* __restrict__ sorted_eid, int E){
  int e = blockIdx.x*blockDim.x + threadIdx.x;
  if (e < E){ int p = atomicAdd(&cursor[dst[e]], 1); sorted_eid[p] = e; }
}

// ---------- W2t build ----------
__global__ void w2t_build(const float* __restrict__ w2, const float* __restrict__ b2,
                          short* __restrict__ W2t){
  int o = blockIdx.x;
  for (int k = threadIdx.x; k < KP; k += blockDim.x){
    float val;
    if (k < 8192){ int i = k >> 7, h = k & 127; val = w2[(size_t)(i*64 + o)*128 + h]; }
    else val = b2[(k - 8192)*64 + o];
    W2t[(size_t)o*KP + k] = f2bf(val);
  }
}

// ---------- fused message GEMM + scatter, A built in registers ----------
// LDS B layout per 32-k chunk: row o (64B), position p (16B slots) holds
// content k-group p^(o&3). Write: load content kq_st, store at kq_st^(o&3).
// Read: content q4 is at position q4^(o&3). (same involution both sides)
__global__ __launch_bounds__(256) void msg_gemm2(
    const short* __restrict__ out_bf, const short* __restrict__ hid_bf,
    const short* __restrict__ W2t, const int* __restrict__ sorted,
    const int* __restrict__ src, const int* __restrict__ dstv,
    float* __restrict__ agg, int E)
{
  __shared__ float sS[64][72];
  __shared__ __align__(16) unsigned char bufB[2][4096];
  __shared__ int eid_s[64];
  __shared__ int dst_s[64];

  const int tid = threadIdx.x;
  const int blk = blockIdx.x;
  const int split = blockIdx.y;

  if (tid < 64){
    int p = blk*64 + tid;
    int e = (p < E) ? sorted[p] : -1;
    eid_s[tid] = e;
    dst_s[tid] = (e >= 0) ? dstv[e] : -1;
  }
  __syncthreads();

  // stage s rows (f32)
  {
    int er = tid >> 2, kq = tid & 3;
    int e = eid_s[er];
    if (e >= 0){
      const short* sp = out_bf + (size_t)src[e]*64 + kq*16;
      short8_t v0 = *(const short8_t*)(sp);
      short8_t v1 = *(const short8_t*)(sp + 8);
      #pragma unroll
      for (int j = 0; j < 8; ++j){
        sS[er][kq*16 + j]     = bf2f(v0[j]);
        sS[er][kq*16 + 8 + j] = bf2f(v1[j]);
      }
    } else {
      #pragma unroll
      for (int j = 0; j < 16; ++j) sS[er][kq*16 + j] = 0.f;
    }
  }

  const int lane = tid & 63, wid = tid >> 6;
  const int r = lane & 15, q4 = lane >> 4;
  const int mh = wid * 16;
  const int eloc = mh + r;

  // h quarters preload (f32 regs)
  float hq0[8], hq1[8], hq2[8], hq3[8];
  {
    int e = eid_s[eloc];
    if (e >= 0){
      const short* hp = hid_bf + (size_t)e*128 + q4*8;
      short8_t v0 = *(const short8_t*)(hp);
      short8_t v1 = *(const short8_t*)(hp + 32);
      short8_t v2 = *(const short8_t*)(hp + 64);
      short8_t v3 = *(const short8_t*)(hp + 96);
      #pragma unroll
      for (int j = 0; j < 8; ++j){
        hq0[j] = bf2f(v0[j]); hq1[j] = bf2f(v1[j]);
        hq2[j] = bf2f(v2[j]); hq3[j] = bf2f(v3[j]);
      }
    } else {
      #pragma unroll
      for (int j = 0; j < 8; ++j){ hq0[j]=0.f; hq1[j]=0.f; hq2[j]=0.f; hq3[j]=0.f; }
    }
  }

  // B staging: thread (o_st, kq_st) loads content k-group kq_st,
  // stores at swizzled slot kq_st ^ (o_st&3).
  const int o_st = tid >> 2, kq_st = tid & 3;
  const int swz_st = kq_st ^ (o_st & 3);
  const uint4* w2p = (const uint4*)(W2t + (size_t)o_st*KP);
  const unsigned stoff = (unsigned)(o_st*64 + swz_st*16);

  // B-frag read offsets (content q4 lives at slot q4^(o&3))
  int boff0, boff1, boff2, boff3;
  {
    int o0 = r, o1 = 16 + r, o2 = 32 + r, o3 = 48 + r;
    boff0 = o0*64 + ((q4 ^ (o0 & 3))*16);
    boff1 = o1*64 + ((q4 ^ (o1 & 3))*16);
    boff2 = o2*64 + ((q4 ^ (o2 & 3))*16);
    boff3 = o3*64 + ((q4 ^ (o3 & 3))*16);
  }

  const int cstart = split * 128;
  const int cend   = split ? 258 : 128;
  int c = cstart;
  uint4 gvA = w2p[(size_t)c*4 + kq_st];
  uint4 gvB = w2p[(size_t)(c+1)*4 + kq_st];

  f32x4_t z4 = {0.f,0.f,0.f,0.f};
  f32x4_t acc0 = z4, acc1 = z4, acc2 = z4, acc3 = z4;
  int ph = 0;
  const int ibase = split * 32;

  __syncthreads();   // sS ready

#define MSG_CHUNK(HQ)                                                   \
  {                                                                     \
    *(uint4*)(bufB[ph] + stoff) = gvA;                                  \
    gvA = gvB;                                                          \
    __syncthreads();                                                    \
    {int nc2 = (c + 2 < cend) ? (c + 2) : (cend - 1);                   \
     gvB = w2p[(size_t)nc2*4 + kq_st];}                                 \
    short8_t b0 = *(const short8_t*)(bufB[ph] + boff0);                 \
    short8_t b1 = *(const short8_t*)(bufB[ph] + boff1);                 \
    short8_t b2 = *(const short8_t*)(bufB[ph] + boff2);                 \
    short8_t b3 = *(const short8_t*)(bufB[ph] + boff3);                 \
    FragA fa;                                                           \
    fa.u[0] = cvt_pk_bf16(sv*HQ[0], sv*HQ[1]);                         \
    fa.u[1] = cvt_pk_bf16(sv*HQ[2], sv*HQ[3]);                         \
    fa.u[2] = cvt_pk_bf16(sv*HQ[4], sv*HQ[5]);                         \
    fa.u[3] = cvt_pk_bf16(sv*HQ[6], sv*HQ[7]);                         \
    acc0 = MFMA16(fa.v, b0, acc0);                                      \
    acc1 = MFMA16(fa.v, b1, acc1);                                      \
    acc2 = MFMA16(fa.v, b2, acc2);                                      \
    acc3 = MFMA16(fa.v, b3, acc3);                                      \
    ph ^= 1; ++c;                                                       \
  }

  #pragma unroll 1
  for (int q = 0; q < 32; ++q){
    float sv = sS[eloc][ibase + q];
    MSG_CHUNK(hq0)
    MSG_CHUNK(hq1)
    MSG_CHUNK(hq2)
    MSG_CHUNK(hq3)
  }

  if (split){
    #pragma unroll 1
    for (int bc = 0; bc < 2; ++bc){
      *(uint4*)(bufB[ph] + stoff) = gvA;
      gvA = gvB;
      __syncthreads();
      {int nc2 = (c + 2 < cend) ? (c + 2) : (cend - 1);
       gvB = w2p[(size_t)nc2*4 + kq_st];}
      short8_t b0 = *(const short8_t*)(bufB[ph] + boff0);
      short8_t b1 = *(const short8_t*)(bufB[ph] + boff1);
      short8_t b2 = *(const short8_t*)(bufB[ph] + boff2);
      short8_t b3 = *(const short8_t*)(bufB[ph] + boff3);
      const float* sp = &sS[eloc][(c - 256)*32 + q4*8];
      float4 s0 = *(const float4*)(sp);
      float4 s1 = *(const float4*)(sp + 4);
      FragA fa;
      fa.u[0] = cvt_pk_bf16(s0.x, s0.y);
      fa.u[1] = cvt_pk_bf16(s0.z, s0.w);
      fa.u[2] = cvt_pk_bf16(s1.x, s1.y);
      fa.u[3] = cvt_pk_bf16(s1.z, s1.w);
      acc0 = MFMA16(fa.v, b0, acc0);
      acc1 = MFMA16(fa.v, b1, acc1);
      acc2 = MFMA16(fa.v, b2, acc2);
      acc3 = MFMA16(fa.v, b3, acc3);
      ph ^= 1; ++c;
    }
  }

  // scatter with run-merge over sorted consecutive dst
  {
    int ebase = mh + q4*4;
    float c0 = 0.f, c1 = 0.f, c2 = 0.f, c3 = 0.f;
    #pragma unroll
    for (int reg = 0; reg < 4; ++reg){
      c0 += acc0[reg]; c1 += acc1[reg]; c2 += acc2[reg]; c3 += acc3[reg];
      int d = dst_s[ebase + reg];
      int dn = (reg < 3) ? dst_s[ebase + reg + 1] : -2;
      if (d != dn){
        if (d >= 0){
          float* ap = agg + (size_t)d*64;
          atomicAdd(ap + r,      c0);
          atomicAdd(ap + 16 + r, c1);
          atomicAdd(ap + 32 + r, c2);
          atomicAdd(ap + 48 + r, c3);
        }
        c0 = c1 = c2 = c3 = 0.f;
      }
    }
  }
}

// ---------- node update (MFMA): M = relu(H@root_w + agg/deg + cb); GRU ----------
__global__ __launch_bounds__(256) void node_mfma(
    const short* __restrict__ out_bf, const float* __restrict__ agg,
    const int* __restrict__ counts,
    const float* __restrict__ root_w, const float* __restrict__ conv_b,
    const float* __restrict__ gwih, const float* __restrict__ gwhh,
    const float* __restrict__ gbih, const float* __restrict__ gbhh,
    float* __restrict__ out, short* __restrict__ out_bf_w, int N)
{
  __shared__ short XH[64*128];
  __shared__ short rootT[64*64];
  __shared__ short Wih_s[192*64];
  __shared__ short Whh_s[192*64];
  __shared__ float rdeg_s[64];
  __shared__ float cb_s[64];

  int tid = threadIdx.x;
  int blk = blockIdx.x;
  int nbase = blk*64;

  {
    int n = tid >> 2, cq = tid & 3;
    int ng = nbase + n;
    short8_t v0 = {0,0,0,0,0,0,0,0}, v1 = v0;
    if (ng < N){
      const short* p = out_bf + (size_t)ng*64;
      v0 = *(const short8_t*)(p + cq*16);
      v1 = *(const short8_t*)(p + cq*16 + 8);
    }
    int c0 = 8 + cq*2;
    *(short8_t*)(XH + n*128 + ((c0     ^ (n & 7))*8)) = v0;
    *(short8_t*)(XH + n*128 + (((c0+1) ^ (n & 7))*8)) = v1;
  }
  {
    int i = tid >> 2, dq = tid & 3;
    #pragma unroll
    for (int j = 0; j < 16; ++j){
      int d = dq*16 + j;
      short v = f2bf(root_w[i*64 + d]);
      rootT[d*64 + (((i >> 3) ^ (d & 7))*8) + (i & 7)] = v;
    }
  }
  if (tid < 192){
    int g = tid;
    short pk[8];
    #pragma unroll
    for (int c = 0; c < 8; ++c){
      #pragma unroll
      for (int j = 0; j < 8; ++j) pk[j] = f2bf(gwih[g*64 + c*8 + j]);
      *(short8_t*)(Wih_s + g*64 + ((c ^ (g & 7))*8)) = *(short8_t*)&pk[0];
    }
    #pragma unroll
    for (int c = 0; c < 8; ++c){
      #pragma unroll
      for (int j = 0; j < 8; ++j) pk[j] = f2bf(gwhh[g*64 + c*8 + j]);
      *(short8_t*)(Whh_s + g*64 + ((c ^ (g & 7))*8)) = *(short8_t*)&pk[0];
    }
  }
  if (tid < 64){
    int ng = nbase + tid;
    int c = (ng < N) ? counts[ng] : 1;
    rdeg_s[tid] = 1.0f / fmaxf((float)c, 1.0f);
    cb_s[tid] = conv_b[tid];
  }
  __syncthreads();

  int lane = tid & 63, wid = tid >> 6;
  int r = lane & 15, q4 = lane >> 4;

  {
    int mh = (wid >> 1)*32, nh = (wid & 1)*32;
    f32x4_t z4 = {0.f,0.f,0.f,0.f};
    f32x4_t c00 = z4, c01 = z4, c10 = z4, c11 = z4;
    #pragma unroll
    for (int ks = 0; ks < 2; ++ks){
      int ck = 8 + ks*4 + q4;
      int swA = (ck ^ (r & 7))*8;
      int swB = ((ks*4 + q4) ^ (r & 7))*8;
      short8_t a0 = *(const short8_t*)(XH + (mh + r)*128 + swA);
      short8_t a1 = *(const short8_t*)(XH + (mh + 16 + r)*128 + swA);
      short8_t b0 = *(const short8_t*)(rootT + (nh + r)*64 + swB);
      short8_t b1 = *(const short8_t*)(rootT + (nh + 16 + r)*64 + swB);
      c00 = MFMA16(a0, b0, c00);
      c01 = MFMA16(a0, b1, c01);
      c10 = MFMA16(a1, b0, c10);
      c11 = MFMA16(a1, b1, c11);
    }
    #pragma unroll
    for (int mm = 0; mm < 2; ++mm){
      #pragma unroll
      for (int nn = 0; nn < 2; ++nn){
        f32x4_t cc = mm == 0 ? (nn == 0 ? c00 : c01) : (nn == 0 ? c10 : c11);
        int d = nh + nn*16 + r;
        #pragma unroll
        for (int reg = 0; reg < 4; ++reg){
          int n = mh + mm*16 + q4*4 + reg;
          int ng = nbase + n;
          float av = (ng < N) ? agg[(size_t)ng*64 + d] : 0.0f;
          float v = cc[reg] + av * rdeg_s[n] + cb_s[d];
          v = fmaxf(v, 0.0f);
          XH[n*128 + (((d >> 3) ^ (n & 7))*8) + (d & 7)] = f2bf(v);
        }
      }
    }
  }
  __syncthreads();

  f32x4_t ax[4][3], ah[4][3];
  {
    f32x4_t z4 = {0.f,0.f,0.f,0.f};
    #pragma unroll
    for (int mt = 0; mt < 4; ++mt)
      #pragma unroll
      for (int gt = 0; gt < 3; ++gt){ ax[mt][gt] = z4; ah[mt][gt] = z4; }
  }
  #pragma unroll
  for (int ks = 0; ks < 2; ++ks){
    int ckM = ks*4 + q4;
    int ckH = 8 + ks*4 + q4;
    int swM = (ckM ^ (r & 7))*8;
    int swH = (ckH ^ (r & 7))*8;
    int swB = ((ks*4 + q4) ^ (r & 7))*8;
    short8_t bx[3], bh[3];
    #pragma unroll
    for (int gt = 0; gt < 3; ++gt){
      int g = gt*64 + wid*16 + r;
      bx[gt] = *(const short8_t*)(Wih_s + g*64 + swB);
      bh[gt] = *(const short8_t*)(Whh_s + g*64 + swB);
    }
    #pragma unroll
    for (int mt = 0; mt < 4; ++mt){
      short8_t aM = *(const short8_t*)(XH + (mt*16 + r)*128 + swM);
      short8_t aH = *(const short8_t*)(XH + (mt*16 + r)*128 + swH);
      #pragma unroll
      for (int gt = 0; gt < 3; ++gt){
        ax[mt][gt] = MFMA16(aM, bx[gt], ax[mt][gt]);
        ah[mt][gt] = MFMA16(aH, bh[gt], ah[mt][gt]);
      }
    }
  }

  {
    int d = wid*16 + r;
    float bir = gbih[d],      bhr = gbhh[d];
    float biz = gbih[64 + d], bhz = gbhh[64 + d];
    float bin_ = gbih[128 + d], bhn = gbhh[128 + d];
    #pragma unroll
    for (int mt = 0; mt < 4; ++mt){
      #pragma unroll
      for (int reg = 0; reg < 4; ++reg){
        int n = mt*16 + q4*4 + reg;
        int ng = nbase + n;
        if (ng < N){
          float gxr = ax[mt][0][reg], gxz = ax[mt][1][reg], gxn = ax[mt][2][reg];
          float ghr = ah[mt][0][reg], ghz = ah[mt][1][reg], ghn = ah[mt][2][reg];
          float rr = sigmoidf_(gxr + ghr + bir + bhr);
          float zz = sigmoidf_(gxz + ghz + biz + bhz);
          float nn = tanhf(gxn + bin_ + rr*(ghn + bhn));
          float h = out[(size_t)ng*64 + d];
          float v = (1.0f - zz)*nn + zz*h;
          out[(size_t)ng*64 + d] = v;
          out_bf_w[(size_t)ng*64 + d] = f2bf(v);
        }
      }
    }
  }
}

// ---------- Set2Set (3 steps) + readout ----------
__global__ __launch_bounds__(64) void set2set_kernel(
    const float* __restrict__ out, const int* __restrict__ bstarts,
    const int* __restrict__ bcounts,
    const float* __restrict__ lwih, const float* __restrict__ lwhh,
    const float* __restrict__ lbih, const float* __restrict__ lbhh,
    const float* __restrict__ l1w, const float* __restrict__ l1b,
    const float* __restrict__ l2w, const float* __restrict__ l2b,
    float* __restrict__ y)
{
  int b = blockIdx.x, d = threadIdx.x;
  __shared__ float qs[128];
  __shared__ float hsl[64];
  __shared__ float ev[2048];
  int s0 = bstarts[b], cnt = bcounts[b];
  if (cnt > 2048) cnt = 2048;
  float hs = 0.f, cs = 0.f;
  qs[d] = 0.f; qs[64 + d] = 0.f;
  __syncthreads();

  for (int step = 0; step < 3; ++step){
    hsl[d] = hs;
    __syncthreads();
    float g[4];
    #pragma unroll
    for (int gg = 0; gg < 4; ++gg){
      int grow = gg*64 + d;
      float a = lbih[grow] + lbhh[grow];
      const float* wi = lwih + grow*128;
      #pragma unroll 8
      for (int k = 0; k < 128; ++k) a = fmaf(qs[k], wi[k], a);
      const float* wh = lwhh + grow*64;
      #pragma unroll 8
      for (int k = 0; k < 64; ++k) a = fmaf(hsl[k], wh[k], a);
      g[gg] = a;
    }
    float ig = sigmoidf_(g[0]);
    float fg = sigmoidf_(g[1]);
    float gg2 = tanhf(g[2]);
    float og = sigmoidf_(g[3]);
    cs = fg*cs + ig*gg2;
    hs = og*tanhf(cs);
    __syncthreads();

    float m = -1e30f;
    for (int idx = 0; idx < cnt; ++idx){
      float p = out[(size_t)(s0 + idx)*64 + d] * hs;
      #pragma unroll
      for (int off = 32; off > 0; off >>= 1) p += __shfl_xor(p, off, 64);
      if (d == 0) ev[idx] = p;
      m = fmaxf(m, p);
    }
    __syncthreads();
    float ls = 0.f;
    for (int idx = d; idx < cnt; idx += 64){
      float a = expf(ev[idx] - m);
      ev[idx] = a;
      ls += a;
    }
    #pragma unroll
    for (int off = 32; off > 0; off >>= 1) ls += __shfl_xor(ls, off, 64);
    __syncthreads();
    float rr = 0.f;
    for (int idx = 0; idx < cnt; ++idx)
      rr = fmaf(ev[idx], out[(size_t)(s0 + idx)*64 + d], rr);
    rr /= ls;
    qs[d] = hs;
    qs[64 + d] = rr;
    __syncthreads();
  }

  float acc = l1b[d];
  const float* w1 = l1w + d*128;
  #pragma unroll 8
  for (int k = 0; k < 128; ++k) acc = fmaf(qs[k], w1[k], acc);
  float v = fmaxf(acc, 0.0f) * l2w[d];
  #pragma unroll
  for (int off = 32; off > 0; off >>= 1) v += __shfl_xor(v, off, 64);
  if (d == 0) y[b] = v + l2b[0];
}

__global__ void copy_kernel(const float* __restrict__ in, float* __restrict__ dst, int n){
  int i = blockIdx.x*blockDim.x + threadIdx.x;
  if (i < n) dst[i] = in[i];
}

extern "C" void kernel_launch(void* const* d_in, const int* in_sizes, int n_in,
                              void* d_out, int out_size, void* d_ws, size_t ws_size,
                              hipStream_t stream){
  const float* x      = (const float*)d_in[0];
  const int*   ei     = (const int*)  d_in[1];
  const float* ea     = (const float*)d_in[2];
  const int*   batch  = (const int*)  d_in[3];
  const float* lin0_w = (const float*)d_in[4];
  const float* lin0_b = (const float*)d_in[5];
  const float* nn1_w  = (const float*)d_in[6];
  const float* nn1_b  = (const float*)d_in[7];
  const float* nn2_w  = (const float*)d_in[8];
  const float* nn2_b  = (const float*)d_in[9];
  const float* root_w = (const float*)d_in[10];
  const float* conv_b = (const float*)d_in[11];
  const float* gwih   = (const float*)d_in[12];
  const float* gwhh   = (const float*)d_in[13];
  const float* gbih   = (const float*)d_in[14];
  const float* gbhh   = (const float*)d_in[15];
  const float* lwih   = (const float*)d_in[16];
  const float* lwhh   = (const float*)d_in[17];
  const float* lbih   = (const float*)d_in[18];
  const float* lbhh   = (const float*)d_in[19];
  const float* l1w    = (const float*)d_in[20];
  const float* l1b    = (const float*)d_in[21];
  const float* l2w    = (const float*)d_in[22];
  const float* l2b    = (const float*)d_in[23];

  const int N = in_sizes[0] / 14;
  const int E = in_sizes[1] / 2;
  const int B = NBG;
  const int* src  = ei;
  const int* dstv = ei + E;

  char* wsp = (char*)d_ws; size_t off = 0;
  auto alloc = [&](size_t bytes)->char* {
    char* p = wsp + off; off += (bytes + 255) & ~((size_t)255); return p;
  };
  float* out     = (float*)alloc((size_t)N*64*4);
  short* out_bf  = (short*)alloc((size_t)N*64*2);
  float* agg     = (float*)alloc((size_t)N*64*4);
  int*   counts  = (int*)  alloc((size_t)N*4);
  int*   starts  = (int*)  alloc((size_t)N*4);
  int*   cursor  = (int*)  alloc((size_t)N*4);
  int*   sorted  = (int*)  alloc((size_t)E*4);
  int*   bcounts = (int*)  alloc((size_t)B*4);
  int*   bstarts = (int*)  alloc((size_t)B*4);
  int*   bcursor = (int*)  alloc((size_t)B*4);
  short* hid_bf  = (short*)alloc((size_t)E*128*2);
  short* W2t     = (short*)alloc((size_t)64*KP*2);

  lin0_kernel<<<N, 64, 0, stream>>>(x, lin0_w, lin0_b, out, out_bf, N);
  ehid_kernel<<<E, 128, 0, stream>>>(ea, nn1_w, nn1_b, hid_bf, E);

  hipMemsetAsync(counts, 0, (size_t)N*4, stream);
  count_kernel<<<(E + 255)/256, 256, 0, stream>>>(dstv, counts, E);
  scan_kernel<<<1, 1024, 0, stream>>>(counts, starts, cursor, N);
  scatter_kernel<<<(E + 255)/256, 256, 0, stream>>>(dstv, cursor, sorted, E);

  hipMemsetAsync(bcounts, 0, (size_t)B*4, stream);
  count_kernel<<<(N + 255)/256, 256, 0, stream>>>(batch, bcounts, N);
  scan_kernel<<<1, 1024, 0, stream>>>(bcounts, bstarts, bcursor, B);

  w2t_build<<<64, 256, 0, stream>>>(nn2_w, nn2_b, W2t);

  int mblocks = (E + 63)/64;
  int nblocks = (N + 63)/64;
  dim3 mg(mblocks, 2);
  for (int it = 0; it < 3; ++it){
    hipMemsetAsync(agg, 0, (size_t)N*64*4, stream);
    msg_gemm2<<<mg, 256, 0, stream>>>(out_bf, hid_bf, W2t, sorted, src, dstv, agg, E);
    node_mfma<<<nblocks, 256, 0, stream>>>(out_bf, agg, counts, root_w, conv_b,
                                           gwih, gwhh, gbih, gbhh, out, out_bf, N);
  }

  set2set_kernel<<<B, 64, 0, stream>>>(out, bstarts, bcounts, lwih, lwhh, lbih, lbhh,
                                       l1w, l1b, l2w, l2b, (float*)d_out);
  copy_kernel<<<((size_t)N*64 + 255)/256, 256, 0, stream>>>(out, (float*)d_out + 300, N*64);
}

// Round 6
// 386.068 us; speedup vs baseline: 84.2095x; 1.1880x over previous
//
#include <hip/hip_runtime.h>
#include <math.h>

#define NBG 300
#define KP 8256   // K = 64*128 (i,h) + 64 bias rows

typedef __attribute__((ext_vector_type(8))) short short8_t;
typedef __attribute__((ext_vector_type(4))) float f32x4_t;

#define MFMA16(a,b,c) __builtin_amdgcn_mfma_f32_16x16x32_bf16(a,b,c,0,0,0)

__device__ __forceinline__ float sigmoidf_(float x){ return 1.0f/(1.0f+expf(-x)); }
__device__ __forceinline__ float bf2f(short s){
  union{unsigned u; float f;} v; v.u = ((unsigned)(unsigned short)s) << 16; return v.f;
}
__device__ __forceinline__ short f2bf(float f){
  union{float f; unsigned u;} v; v.f = f;
  unsigned r = (v.u + 0x7fffu + ((v.u >> 16) & 1u)) >> 16;
  return (short)r;
}
__device__ __forceinline__ unsigned cvt_pk_bf16(float lo, float hi){
  unsigned r;
  asm volatile("v_cvt_pk_bf16_f32 %0, %1, %2" : "=v"(r) : "v"(lo), "v"(hi));
  return r;
}
union FragA { short8_t v; unsigned u[4]; };

// ---------- lin0 ----------
__global__ void lin0_kernel(const float* __restrict__ x, const float* __restrict__ w,
                            const float* __restrict__ b, float* __restrict__ out,
                            short* __restrict__ out_bf, int N){
  int n = blockIdx.x; int d = threadIdx.x;
  __shared__ float xs[16];
  if (d < 14) xs[d] = x[n*14 + d];
  __syncthreads();
  float acc = b[d];
  #pragma unroll
  for (int k = 0; k < 14; ++k) acc = fmaf(xs[k], w[d*14 + k], acc);
  float v = fmaxf(acc, 0.0f);
  out[n*64 + d] = v;
  out_bf[n*64 + d] = f2bf(v);
}

// ---------- edge MLP hidden (bf16 out) ----------
__global__ void ehid_kernel(const float* __restrict__ ea, const float* __restrict__ w,
                            const float* __restrict__ b, short* __restrict__ hid_bf, int E){
  int e = blockIdx.x; int t = threadIdx.x;
  __shared__ float as[4];
  if (t < 4) as[t] = ea[e*4 + t];
  __syncthreads();
  float acc = b[t];
  #pragma unroll
  for (int k = 0; k < 4; ++k) acc = fmaf(as[k], w[t*4 + k], acc);
  hid_bf[(size_t)e*128 + t] = f2bf(fmaxf(acc, 0.0f));
}

// ---------- counting sort infra ----------
__global__ void count_kernel(const int* __restrict__ idx, int* __restrict__ counts, int len){
  int e = blockIdx.x*blockDim.x + threadIdx.x;
  if (e < len) atomicAdd(&counts[idx[e]], 1);
}

__global__ __launch_bounds__(1024) void scan_kernel(const int* __restrict__ counts,
    int* __restrict__ starts, int* __restrict__ cursor, int N){
  __shared__ int part[1024];
  int t = threadIdx.x;
  int per = (N + 1023) >> 10;
  int base = t * per;
  int s = 0;
  for (int j = 0; j < per; ++j){ int idx = base + j; if (idx < N) s += counts[idx]; }
  part[t] = s;
  __syncthreads();
  for (int off = 1; off < 1024; off <<= 1){
    int v = (t >= off) ? part[t - off] : 0;
    __syncthreads();
    part[t] += v;
    __syncthreads();
  }
  int run = (t == 0) ? 0 : part[t-1];
  for (int j = 0; j < per; ++j){
    int idx = base + j;
    if (idx < N){ starts[idx] = run; cursor[idx] = run; run += counts[idx]; }
  }
}

__global__ void scatter_kernel(const int* __restrict__ dst, int* __restrict__ cursor,
                               int* __restrict__ sorted_eid, int E){
  int e = blockIdx.x*blockDim.x + threadIdx.x;
  if (e < E){ int p = atomicAdd(&cursor[dst[e]], 1); sorted_eid[p] = e; }
}

// ---------- W2t build ----------
__global__ void w2t_build(const float* __restrict__ w2, const float* __restrict__ b2,
                          short* __restrict__ W2t){
  int o = blockIdx.x;
  for (int k = threadIdx.x; k < KP; k += blockDim.x){
    float val;
    if (k < 8192){ int i = k >> 7, h = k & 127; val = w2[(size_t)(i*64 + o)*128 + h]; }
    else val = b2[(k - 8192)*64 + o];
    W2t[(size_t)o*KP + k] = f2bf(val);
  }
}

// ---------- fused message GEMM + scatter, A built in registers ----------
__global__ __launch_bounds__(256) void msg_gemm2(
    const short* __restrict__ out_bf, const short* __restrict__ hid_bf,
    const short* __restrict__ W2t, const int* __restrict__ sorted,
    const int* __restrict__ src, const int* __restrict__ dstv,
    float* __restrict__ agg, int E)
{
  __shared__ float sS[64][72];
  __shared__ __align__(16) unsigned char bufB[2][4096];
  __shared__ int eid_s[64];
  __shared__ int dst_s[64];

  const int tid = threadIdx.x;
  const int blk = blockIdx.x;
  const int split = blockIdx.y;

  if (tid < 64){
    int p = blk*64 + tid;
    int e = (p < E) ? sorted[p] : -1;
    eid_s[tid] = e;
    dst_s[tid] = (e >= 0) ? dstv[e] : -1;
  }
  __syncthreads();

  // stage s rows (f32)
  {
    int er = tid >> 2, kq = tid & 3;
    int e = eid_s[er];
    if (e >= 0){
      const short* sp = out_bf + (size_t)src[e]*64 + kq*16;
      short8_t v0 = *(const short8_t*)(sp);
      short8_t v1 = *(const short8_t*)(sp + 8);
      #pragma unroll
      for (int j = 0; j < 8; ++j){
        sS[er][kq*16 + j]     = bf2f(v0[j]);
        sS[er][kq*16 + 8 + j] = bf2f(v1[j]);
      }
    } else {
      #pragma unroll
      for (int j = 0; j < 16; ++j) sS[er][kq*16 + j] = 0.f;
    }
  }

  const int lane = tid & 63, wid = tid >> 6;
  const int r = lane & 15, q4 = lane >> 4;
  const int mh = wid * 16;
  const int eloc = mh + r;

  // h quarters preload (f32 regs)
  float hq0[8], hq1[8], hq2[8], hq3[8];
  {
    int e = eid_s[eloc];
    if (e >= 0){
      const short* hp = hid_bf + (size_t)e*128 + q4*8;
      short8_t v0 = *(const short8_t*)(hp);
      short8_t v1 = *(const short8_t*)(hp + 32);
      short8_t v2 = *(const short8_t*)(hp + 64);
      short8_t v3 = *(const short8_t*)(hp + 96);
      #pragma unroll
      for (int j = 0; j < 8; ++j){
        hq0[j] = bf2f(v0[j]); hq1[j] = bf2f(v1[j]);
        hq2[j] = bf2f(v2[j]); hq3[j] = bf2f(v3[j]);
      }
    } else {
      #pragma unroll
      for (int j = 0; j < 8; ++j){ hq0[j]=0.f; hq1[j]=0.f; hq2[j]=0.f; hq3[j]=0.f; }
    }
  }

  // B staging: thread (o_st, kq_st) loads content k-group kq_st,
  // stores at swizzled slot kq_st ^ (o_st&3).
  const int o_st = tid >> 2, kq_st = tid & 3;
  const int swz_st = kq_st ^ (o_st & 3);
  const uint4* w2p = (const uint4*)(W2t + (size_t)o_st*KP);
  const unsigned stoff = (unsigned)(o_st*64 + swz_st*16);

  // B-frag read offsets (content q4 lives at slot q4^(o&3))
  int boff0, boff1, boff2, boff3;
  {
    int o0 = r, o1 = 16 + r, o2 = 32 + r, o3 = 48 + r;
    boff0 = o0*64 + ((q4 ^ (o0 & 3))*16);
    boff1 = o1*64 + ((q4 ^ (o1 & 3))*16);
    boff2 = o2*64 + ((q4 ^ (o2 & 3))*16);
    boff3 = o3*64 + ((q4 ^ (o3 & 3))*16);
  }

  const int cstart = split * 128;
  const int cend   = split ? 258 : 128;
  int c = cstart;
  uint4 gvA = w2p[(size_t)c*4 + kq_st];
  uint4 gvB = w2p[(size_t)(c+1)*4 + kq_st];

  f32x4_t z4 = {0.f,0.f,0.f,0.f};
  f32x4_t acc0 = z4, acc1 = z4, acc2 = z4, acc3 = z4;
  int ph = 0;
  const int ibase = split * 32;

  __syncthreads();   // sS ready

#define MSG_CHUNK(HQ)                                                   \
  {                                                                     \
    *(uint4*)(bufB[ph] + stoff) = gvA;                                  \
    gvA = gvB;                                                          \
    __syncthreads();                                                    \
    {int nc2 = (c + 2 < cend) ? (c + 2) : (cend - 1);                   \
     gvB = w2p[(size_t)nc2*4 + kq_st];}                                 \
    short8_t b0 = *(const short8_t*)(bufB[ph] + boff0);                 \
    short8_t b1 = *(const short8_t*)(bufB[ph] + boff1);                 \
    short8_t b2 = *(const short8_t*)(bufB[ph] + boff2);                 \
    short8_t b3 = *(const short8_t*)(bufB[ph] + boff3);                 \
    FragA fa;                                                           \
    fa.u[0] = cvt_pk_bf16(sv*HQ[0], sv*HQ[1]);                         \
    fa.u[1] = cvt_pk_bf16(sv*HQ[2], sv*HQ[3]);                         \
    fa.u[2] = cvt_pk_bf16(sv*HQ[4], sv*HQ[5]);                         \
    fa.u[3] = cvt_pk_bf16(sv*HQ[6], sv*HQ[7]);                         \
    acc0 = MFMA16(fa.v, b0, acc0);                                      \
    acc1 = MFMA16(fa.v, b1, acc1);                                      \
    acc2 = MFMA16(fa.v, b2, acc2);                                      \
    acc3 = MFMA16(fa.v, b3, acc3);                                      \
    ph ^= 1; ++c;                                                       \
  }

  #pragma unroll 1
  for (int q = 0; q < 32; ++q){
    float sv = sS[eloc][ibase + q];
    MSG_CHUNK(hq0)
    MSG_CHUNK(hq1)
    MSG_CHUNK(hq2)
    MSG_CHUNK(hq3)
  }

  if (split){
    #pragma unroll 1
    for (int bc = 0; bc < 2; ++bc){
      *(uint4*)(bufB[ph] + stoff) = gvA;
      gvA = gvB;
      __syncthreads();
      {int nc2 = (c + 2 < cend) ? (c + 2) : (cend - 1);
       gvB = w2p[(size_t)nc2*4 + kq_st];}
      short8_t b0 = *(const short8_t*)(bufB[ph] + boff0);
      short8_t b1 = *(const short8_t*)(bufB[ph] + boff1);
      short8_t b2 = *(const short8_t*)(bufB[ph] + boff2);
      short8_t b3 = *(const short8_t*)(bufB[ph] + boff3);
      const float* sp = &sS[eloc][(c - 256)*32 + q4*8];
      float4 s0 = *(const float4*)(sp);
      float4 s1 = *(const float4*)(sp + 4);
      FragA fa;
      fa.u[0] = cvt_pk_bf16(s0.x, s0.y);
      fa.u[1] = cvt_pk_bf16(s0.z, s0.w);
      fa.u[2] = cvt_pk_bf16(s1.x, s1.y);
      fa.u[3] = cvt_pk_bf16(s1.z, s1.w);
      acc0 = MFMA16(fa.v, b0, acc0);
      acc1 = MFMA16(fa.v, b1, acc1);
      acc2 = MFMA16(fa.v, b2, acc2);
      acc3 = MFMA16(fa.v, b3, acc3);
      ph ^= 1; ++c;
    }
  }

  // scatter with run-merge over sorted consecutive dst
  {
    int ebase = mh + q4*4;
    float c0 = 0.f, c1 = 0.f, c2 = 0.f, c3 = 0.f;
    #pragma unroll
    for (int reg = 0; reg < 4; ++reg){
      c0 += acc0[reg]; c1 += acc1[reg]; c2 += acc2[reg]; c3 += acc3[reg];
      int d = dst_s[ebase + reg];
      int dn = (reg < 3) ? dst_s[ebase + reg + 1] : -2;
      if (d != dn){
        if (d >= 0){
          float* ap = agg + (size_t)d*64;
          atomicAdd(ap + r,      c0);
          atomicAdd(ap + 16 + r, c1);
          atomicAdd(ap + 32 + r, c2);
          atomicAdd(ap + 48 + r, c3);
        }
        c0 = c1 = c2 = c3 = 0.f;
      }
    }
  }
}

// ---------- node update (MFMA): M = relu(H@root_w + agg/deg + cb); GRU ----------
__global__ __launch_bounds__(256) void node_mfma(
    const short* __restrict__ out_bf, const float* __restrict__ agg,
    const int* __restrict__ counts,
    const float* __restrict__ root_w, const float* __restrict__ conv_b,
    const float* __restrict__ gwih, const float* __restrict__ gwhh,
    const float* __restrict__ gbih, const float* __restrict__ gbhh,
    float* __restrict__ out, short* __restrict__ out_bf_w,
    float* __restrict__ out_dup, int N)
{
  __shared__ short XH[64*128];
  __shared__ short rootT[64*64];
  __shared__ short Wih_s[192*64];
  __shared__ short Whh_s[192*64];
  __shared__ float rdeg_s[64];
  __shared__ float cb_s[64];

  int tid = threadIdx.x;
  int blk = blockIdx.x;
  int nbase = blk*64;

  {
    int n = tid >> 2, cq = tid & 3;
    int ng = nbase + n;
    short8_t v0 = {0,0,0,0,0,0,0,0}, v1 = v0;
    if (ng < N){
      const short* p = out_bf + (size_t)ng*64;
      v0 = *(const short8_t*)(p + cq*16);
      v1 = *(const short8_t*)(p + cq*16 + 8);
    }
    int c0 = 8 + cq*2;
    *(short8_t*)(XH + n*128 + ((c0     ^ (n & 7))*8)) = v0;
    *(short8_t*)(XH + n*128 + (((c0+1) ^ (n & 7))*8)) = v1;
  }
  {
    int i = tid >> 2, dq = tid & 3;
    #pragma unroll
    for (int j = 0; j < 16; ++j){
      int d = dq*16 + j;
      short v = f2bf(root_w[i*64 + d]);
      rootT[d*64 + (((i >> 3) ^ (d & 7))*8) + (i & 7)] = v;
    }
  }
  if (tid < 192){
    int g = tid;
    short pk[8];
    #pragma unroll
    for (int c = 0; c < 8; ++c){
      #pragma unroll
      for (int j = 0; j < 8; ++j) pk[j] = f2bf(gwih[g*64 + c*8 + j]);
      *(short8_t*)(Wih_s + g*64 + ((c ^ (g & 7))*8)) = *(short8_t*)&pk[0];
    }
    #pragma unroll
    for (int c = 0; c < 8; ++c){
      #pragma unroll
      for (int j = 0; j < 8; ++j) pk[j] = f2bf(gwhh[g*64 + c*8 + j]);
      *(short8_t*)(Whh_s + g*64 + ((c ^ (g & 7))*8)) = *(short8_t*)&pk[0];
    }
  }
  if (tid < 64){
    int ng = nbase + tid;
    int c = (ng < N) ? counts[ng] : 1;
    rdeg_s[tid] = 1.0f / fmaxf((float)c, 1.0f);
    cb_s[tid] = conv_b[tid];
  }
  __syncthreads();

  int lane = tid & 63, wid = tid >> 6;
  int r = lane & 15, q4 = lane >> 4;

  {
    int mh = (wid >> 1)*32, nh = (wid & 1)*32;
    f32x4_t z4 = {0.f,0.f,0.f,0.f};
    f32x4_t c00 = z4, c01 = z4, c10 = z4, c11 = z4;
    #pragma unroll
    for (int ks = 0; ks < 2; ++ks){
      int ck = 8 + ks*4 + q4;
      int swA = (ck ^ (r & 7))*8;
      int swB = ((ks*4 + q4) ^ (r & 7))*8;
      short8_t a0 = *(const short8_t*)(XH + (mh + r)*128 + swA);
      short8_t a1 = *(const short8_t*)(XH + (mh + 16 + r)*128 + swA);
      short8_t b0 = *(const short8_t*)(rootT + (nh + r)*64 + swB);
      short8_t b1 = *(const short8_t*)(rootT + (nh + 16 + r)*64 + swB);
      c00 = MFMA16(a0, b0, c00);
      c01 = MFMA16(a0, b1, c01);
      c10 = MFMA16(a1, b0, c10);
      c11 = MFMA16(a1, b1, c11);
    }
    #pragma unroll
    for (int mm = 0; mm < 2; ++mm){
      #pragma unroll
      for (int nn = 0; nn < 2; ++nn){
        f32x4_t cc = mm == 0 ? (nn == 0 ? c00 : c01) : (nn == 0 ? c10 : c11);
        int d = nh + nn*16 + r;
        #pragma unroll
        for (int reg = 0; reg < 4; ++reg){
          int n = mh + mm*16 + q4*4 + reg;
          int ng = nbase + n;
          float av = (ng < N) ? agg[(size_t)ng*64 + d] : 0.0f;
          float v = cc[reg] + av * rdeg_s[n] + cb_s[d];
          v = fmaxf(v, 0.0f);
          XH[n*128 + (((d >> 3) ^ (n & 7))*8) + (d & 7)] = f2bf(v);
        }
      }
    }
  }
  __syncthreads();

  f32x4_t ax[4][3], ah[4][3];
  {
    f32x4_t z4 = {0.f,0.f,0.f,0.f};
    #pragma unroll
    for (int mt = 0; mt < 4; ++mt)
      #pragma unroll
      for (int gt = 0; gt < 3; ++gt){ ax[mt][gt] = z4; ah[mt][gt] = z4; }
  }
  #pragma unroll
  for (int ks = 0; ks < 2; ++ks){
    int ckM = ks*4 + q4;
    int ckH = 8 + ks*4 + q4;
    int swM = (ckM ^ (r & 7))*8;
    int swH = (ckH ^ (r & 7))*8;
    int swB = ((ks*4 + q4) ^ (r & 7))*8;
    short8_t bx[3], bh[3];
    #pragma unroll
    for (int gt = 0; gt < 3; ++gt){
      int g = gt*64 + wid*16 + r;
      bx[gt] = *(const short8_t*)(Wih_s + g*64 + swB);
      bh[gt] = *(const short8_t*)(Whh_s + g*64 + swB);
    }
    #pragma unroll
    for (int mt = 0; mt < 4; ++mt){
      short8_t aM = *(const short8_t*)(XH + (mt*16 + r)*128 + swM);
      short8_t aH = *(const short8_t*)(XH + (mt*16 + r)*128 + swH);
      #pragma unroll
      for (int gt = 0; gt < 3; ++gt){
        ax[mt][gt] = MFMA16(aM, bx[gt], ax[mt][gt]);
        ah[mt][gt] = MFMA16(aH, bh[gt], ah[mt][gt]);
      }
    }
  }

  {
    int d = wid*16 + r;
    float bir = gbih[d],      bhr = gbhh[d];
    float biz = gbih[64 + d], bhz = gbhh[64 + d];
    float bin_ = gbih[128 + d], bhn = gbhh[128 + d];
    #pragma unroll
    for (int mt = 0; mt < 4; ++mt){
      #pragma unroll
      for (int reg = 0; reg < 4; ++reg){
        int n = mt*16 + q4*4 + reg;
        int ng = nbase + n;
        if (ng < N){
          float gxr = ax[mt][0][reg], gxz = ax[mt][1][reg], gxn = ax[mt][2][reg];
          float ghr = ah[mt][0][reg], ghz = ah[mt][1][reg], ghn = ah[mt][2][reg];
          float rr = sigmoidf_(gxr + ghr + bir + bhr);
          float zz = sigmoidf_(gxz + ghz + biz + bhz);
          float nn = tanhf(gxn + bin_ + rr*(ghn + bhn));
          float h = out[(size_t)ng*64 + d];
          float v = (1.0f - zz)*nn + zz*h;
          out[(size_t)ng*64 + d] = v;
          out_bf_w[(size_t)ng*64 + d] = f2bf(v);
          if (out_dup) out_dup[(size_t)ng*64 + d] = v;
        }
      }
    }
  }
}

// ---------- Set2Set (3 steps) + readout, 256 threads, node-parallel ----------
__global__ __launch_bounds__(256) void set2set_kernel(
    const float* __restrict__ out, const int* __restrict__ bstarts,
    const int* __restrict__ bcounts,
    const float* __restrict__ lwih, const float* __restrict__ lwhh,
    const float* __restrict__ lbih, const float* __restrict__ lbhh,
    const float* __restrict__ l1w, const float* __restrict__ l1b,
    const float* __restrict__ l2w, const float* __restrict__ l2b,
    float* __restrict__ y)
{
  int b = blockIdx.x, t = threadIdx.x;
  int lane = t & 63, wid = t >> 6;
  __shared__ float qs[128];
  __shared__ float hsl[64], hs_s[64], cs_s[64];
  __shared__ float ev[512];
  __shared__ float red[256];
  __shared__ float rpart[4][64];
  __shared__ float scal[2];

  int s0 = bstarts[b], cnt = bcounts[b];
  if (cnt > 512) cnt = 512;
  if (t < 64){ hs_s[t] = 0.f; cs_s[t] = 0.f; }
  if (t < 128) qs[t] = 0.f;
  __syncthreads();

  for (int step = 0; step < 3; ++step){
    if (t < 64) hsl[t] = hs_s[t];
    __syncthreads();
    // ---- LSTM gates: thread t owns gate-row t (0..255) ----
    {
      float a0 = lbih[t] + lbhh[t], a1 = 0.f, a2 = 0.f, a3 = 0.f;
      const float* wi = lwih + t*128;
      #pragma unroll
      for (int kq = 0; kq < 32; ++kq){
        float4 w4 = *(const float4*)(wi + kq*4);
        a0 = fmaf(qs[kq*4+0], w4.x, a0);
        a1 = fmaf(qs[kq*4+1], w4.y, a1);
        a2 = fmaf(qs[kq*4+2], w4.z, a2);
        a3 = fmaf(qs[kq*4+3], w4.w, a3);
      }
      const float* wh = lwhh + t*64;
      #pragma unroll
      for (int kq = 0; kq < 16; ++kq){
        float4 w4 = *(const float4*)(wh + kq*4);
        a0 = fmaf(hsl[kq*4+0], w4.x, a0);
        a1 = fmaf(hsl[kq*4+1], w4.y, a1);
        a2 = fmaf(hsl[kq*4+2], w4.z, a2);
        a3 = fmaf(hsl[kq*4+3], w4.w, a3);
      }
      red[t] = (a0 + a1) + (a2 + a3);
    }
    __syncthreads();
    if (t < 64){
      float ig = sigmoidf_(red[t]);
      float fg = sigmoidf_(red[64 + t]);
      float gg = tanhf(red[128 + t]);
      float og = sigmoidf_(red[192 + t]);
      float c = fg*cs_s[t] + ig*gg;
      cs_s[t] = c;
      hs_s[t] = og*tanhf(c);
    }
    __syncthreads();

    // ---- e-phase: node-parallel dot(out[n], hs) ----
    float lmax = -1e30f;
    for (int idx = t; idx < cnt; idx += 256){
      const float* row = out + (size_t)(s0 + idx)*64;
      float a0 = 0.f, a1 = 0.f, a2 = 0.f, a3 = 0.f;
      #pragma unroll
      for (int kq = 0; kq < 16; ++kq){
        float4 v = *(const float4*)(row + kq*4);
        a0 = fmaf(v.x, hs_s[kq*4+0], a0);
        a1 = fmaf(v.y, hs_s[kq*4+1], a1);
        a2 = fmaf(v.z, hs_s[kq*4+2], a2);
        a3 = fmaf(v.w, hs_s[kq*4+3], a3);
      }
      float acc = (a0 + a1) + (a2 + a3);
      ev[idx] = acc;
      lmax = fmaxf(lmax, acc);
    }
    red[t] = lmax;
    __syncthreads();
    #pragma unroll
    for (int off = 128; off > 0; off >>= 1){
      if (t < off) red[t] = fmaxf(red[t], red[t + off]);
      __syncthreads();
    }
    if (t == 0) scal[0] = red[0];
    __syncthreads();
    float m = scal[0];

    float ls = 0.f;
    for (int idx = t; idx < cnt; idx += 256){
      float a = expf(ev[idx] - m);
      ev[idx] = a;
      ls += a;
    }
    red[t] = ls;
    __syncthreads();
    #pragma unroll
    for (int off = 128; off > 0; off >>= 1){
      if (t < off) red[t] += red[t + off];
      __syncthreads();
    }
    if (t == 0) scal[1] = red[0];
    __syncthreads();
    float lst = scal[1];

    // ---- r-phase: wave wid covers nodes wid, wid+4, ...; lane = dim ----
    float part = 0.f;
    for (int idx = wid; idx < cnt; idx += 4)
      part = fmaf(ev[idx], out[(size_t)(s0 + idx)*64 + lane], part);
    rpart[wid][lane] = part;
    __syncthreads();
    if (t < 64){
      float r = (rpart[0][t] + rpart[1][t]) + (rpart[2][t] + rpart[3][t]);
      r = (cnt > 0) ? r / lst : 0.f;
      qs[t] = hs_s[t];
      qs[64 + t] = r;
    }
    __syncthreads();
  }

  // ---- readout ----
  if (t < 64){
    float a0 = l1b[t], a1 = 0.f, a2 = 0.f, a3 = 0.f;
    const float* w1 = l1w + t*128;
    #pragma unroll
    for (int kq = 0; kq < 32; ++kq){
      float4 w4 = *(const float4*)(w1 + kq*4);
      a0 = fmaf(qs[kq*4+0], w4.x, a0);
      a1 = fmaf(qs[kq*4+1], w4.y, a1);
      a2 = fmaf(qs[kq*4+2], w4.z, a2);
      a3 = fmaf(qs[kq*4+3], w4.w, a3);
    }
    float acc = (a0 + a1) + (a2 + a3);
    float v = fmaxf(acc, 0.0f) * l2w[t];
    #pragma unroll
    for (int off = 32; off > 0; off >>= 1) v += __shfl_xor(v, off, 64);
    if (t == 0) y[b] = v + l2b[0];
  }
}

extern "C" void kernel_launch(void* const* d_in, const int* in_sizes, int n_in,
                              void* d_out, int out_size, void* d_ws, size_t ws_size,
                              hipStream_t stream){
  const float* x      = (const float*)d_in[0];
  const int*   ei     = (const int*)  d_in[1];
  const float* ea     = (const float*)d_in[2];
  const int*   batch  = (const int*)  d_in[3];
  const float* lin0_w = (const float*)d_in[4];
  const float* lin0_b = (const float*)d_in[5];
  const float* nn1_w  = (const float*)d_in[6];
  const float* nn1_b  = (const float*)d_in[7];
  const float* nn2_w  = (const float*)d_in[8];
  const float* nn2_b  = (const float*)d_in[9];
  const float* root_w = (const float*)d_in[10];
  const float* conv_b = (const float*)d_in[11];
  const float* gwih   = (const float*)d_in[12];
  const float* gwhh   = (const float*)d_in[13];
  const float* gbih   = (const float*)d_in[14];
  const float* gbhh   = (const float*)d_in[15];
  const float* lwih   = (const float*)d_in[16];
  const float* lwhh   = (const float*)d_in[17];
  const float* lbih   = (const float*)d_in[18];
  const float* lbhh   = (const float*)d_in[19];
  const float* l1w    = (const float*)d_in[20];
  const float* l1b    = (const float*)d_in[21];
  const float* l2w    = (const float*)d_in[22];
  const float* l2b    = (const float*)d_in[23];

  const int N = in_sizes[0] / 14;
  const int E = in_sizes[1] / 2;
  const int B = NBG;
  const int* src  = ei;
  const int* dstv = ei + E;

  char* wsp = (char*)d_ws; size_t off = 0;
  auto alloc = [&](size_t bytes)->char* {
    char* p = wsp + off; off += (bytes + 255) & ~((size_t)255); return p;
  };
  float* out     = (float*)alloc((size_t)N*64*4);
  short* out_bf  = (short*)alloc((size_t)N*64*2);
  float* agg     = (float*)alloc((size_t)N*64*4);
  int*   counts  = (int*)  alloc((size_t)N*4);
  int*   starts  = (int*)  alloc((size_t)N*4);
  int*   cursor  = (int*)  alloc((size_t)N*4);
  int*   sorted  = (int*)  alloc((size_t)E*4);
  int*   bcounts = (int*)  alloc((size_t)B*4);
  int*   bstarts = (int*)  alloc((size_t)B*4);
  int*   bcursor = (int*)  alloc((size_t)B*4);
  short* hid_bf  = (short*)alloc((size_t)E*128*2);
  short* W2t     = (short*)alloc((size_t)64*KP*2);

  lin0_kernel<<<N, 64, 0, stream>>>(x, lin0_w, lin0_b, out, out_bf, N);
  ehid_kernel<<<E, 128, 0, stream>>>(ea, nn1_w, nn1_b, hid_bf, E);

  hipMemsetAsync(counts, 0, (size_t)N*4, stream);
  count_kernel<<<(E + 255)/256, 256, 0, stream>>>(dstv, counts, E);
  scan_kernel<<<1, 1024, 0, stream>>>(counts, starts, cursor, N);
  scatter_kernel<<<(E + 255)/256, 256, 0, stream>>>(dstv, cursor, sorted, E);

  hipMemsetAsync(bcounts, 0, (size_t)B*4, stream);
  count_kernel<<<(N + 255)/256, 256, 0, stream>>>(batch, bcounts, N);
  scan_kernel<<<1, 1024, 0, stream>>>(bcounts, bstarts, bcursor, B);

  w2t_build<<<64, 256, 0, stream>>>(nn2_w, nn2_b, W2t);

  int mblocks = (E + 63)/64;
  int nblocks = (N + 63)/64;
  dim3 mg(mblocks, 2);
  for (int it = 0; it < 3; ++it){
    hipMemsetAsync(agg, 0, (size_t)N*64*4, stream);
    msg_gemm2<<<mg, 256, 0, stream>>>(out_bf, hid_bf, W2t, sorted, src, dstv, agg, E);
    node_mfma<<<nblocks, 256, 0, stream>>>(out_bf, agg, counts, root_w, conv_b,
                                           gwih, gwhh, gbih, gbhh, out, out_bf,
                                           (it == 2) ? ((float*)d_out + 300) : nullptr, N);
  }

  set2set_kernel<<<B, 256, 0, stream>>>(out, bstarts, bcounts, lwih, lwhh, lbih, lbhh,
                                        l1w, l1b, l2w, l2b, (float*)d_out);
}